// Round 10
// baseline (4972.155 us; speedup 1.0000x reference)
//
#include <hip/hip_runtime.h>
#include <hip/hip_bf16.h>
#include <math.h>

typedef __attribute__((ext_vector_type(8))) short bf16x8;
typedef __attribute__((ext_vector_type(8))) unsigned short ushort8;
typedef __attribute__((ext_vector_type(4))) float f32x4;

// block roles
#define NLSTM 32
#define ATTN0 32
#define NATTN 64
#define HA0   96
#define NHA   8
#define LOG0  104
#define NLOG  125
#define NBLK  229

// flag lines (128B each): [0,32) lstm arrival, [32,96) ctx arrival,
// [96,104) ha arrival, [104,112) decGen replicas, [112,120) logGen replicas,
// 120 logDone
#define FL_LSTM 0
#define FL_CTX  32
#define FL_HA   96
#define FL_DGR  104
#define FL_LGR  112
#define FL_LOGD 120

static __device__ inline unsigned short f2bf(float f) {
    unsigned u = __builtin_bit_cast(unsigned, f);
    u += 0x7fffu + ((u >> 16) & 1u);   // RNE
    return (unsigned short)(u >> 16);
}
static __device__ inline float bf2f(unsigned short u) {
    return __builtin_bit_cast(float, ((unsigned)u) << 16);
}

// ---- LLC-coherent (L1/L2-bypassing) access helpers: no cache maintenance ----
__device__ inline ushort8 llc_load8_wait(const unsigned short* p) {
    ushort8 v;
    asm volatile("global_load_dwordx4 %0, %1, off sc0 sc1\n\ts_waitcnt vmcnt(0)"
                 : "=v"(v) : "v"(p) : "memory");
    return v;
}
#define LLC_LOAD8_ISSUE(dst, p) \
    asm volatile("global_load_dwordx4 %0, %1, off sc0 sc1" : "=v"(dst) : "v"(p))
#define VMCNT0() do { asm volatile("s_waitcnt vmcnt(0)" ::: "memory"); \
                      __builtin_amdgcn_sched_barrier(0); } while (0)
#define WAITVM(N) do { asm volatile("s_waitcnt vmcnt(" #N ")" ::: "memory"); \
                       __builtin_amdgcn_sched_barrier(0); } while (0)
__device__ inline void llc_store16(unsigned short* p, unsigned short v) {
    unsigned uv = v;
    asm volatile("global_store_short %0, %1, off sc0 sc1" :: "v"(p), "v"(uv) : "memory");
}
__device__ inline void llc_store32(void* p, unsigned v) {
    asm volatile("global_store_dword %0, %1, off sc0 sc1" :: "v"(p), "v"(v) : "memory");
}
__device__ inline void llc_storef(float* p, float v) {
    asm volatile("global_store_dword %0, %1, off sc0 sc1" :: "v"(p), "v"(__builtin_bit_cast(unsigned, v)) : "memory");
}

// ---------------- sync primitives ----------------
// multi-line gather poll (used only where the poller count is small)
__device__ inline void poll_flags(const unsigned* fl, int mask, unsigned target) {
    if (threadIdx.x < 64) {
        const unsigned* p = fl + (threadIdx.x & mask) * 32;
        while (true) {
            unsigned v;
            asm volatile("global_load_dword %0, %1, off sc0 sc1\n\ts_waitcnt vmcnt(0)"
                         : "=v"(v) : "v"(p) : "memory");
            if (__all((int)(v >= target))) break;
            __builtin_amdgcn_s_sleep(1);
        }
    }
    __syncthreads();
}

// single-line single-lane poll (cheap for many pollers)
__device__ inline void poll_one(const unsigned* line, unsigned target) {
    if (threadIdx.x == 0) {
        while (true) {
            unsigned v;
            asm volatile("global_load_dword %0, %1, off sc0 sc1\n\ts_waitcnt vmcnt(0)"
                         : "=v"(v) : "v"(line) : "memory");
            if (v >= target) break;
            __builtin_amdgcn_s_sleep(1);
        }
    }
    __syncthreads();
}

// all threads drain own sc1 stores, then block sync (call before flag store)
__device__ inline void drain_sync() {
    asm volatile("s_waitcnt vmcnt(0)" ::: "memory");
    __syncthreads();
}

__device__ inline void wait_count(unsigned* f, unsigned target) {
    if (threadIdx.x == 0) {
        while (__hip_atomic_load(f, __ATOMIC_RELAXED, __HIP_MEMORY_SCOPE_AGENT) < target)
            __builtin_amdgcn_s_sleep(4);
    }
    __syncthreads();
}

__device__ inline void signal_count(unsigned* f) {
    drain_sync();
    if (threadIdx.x == 0)
        __hip_atomic_fetch_add(f, 1u, __ATOMIC_RELAXED, __HIP_MEMORY_SCOPE_AGENT);
}

// ---------------- one-time conversion kernels ----------------

__global__ void conv_lstm_w2(unsigned short* dstX, unsigned short* dstH,
                             const float* __restrict__ Wih,
                             const float* __restrict__ Whh) {
    int idx = blockIdx.x * 256 + threadIdx.x;      // < 2048*512
    int np = idx >> 9, k = idx & 511;
    int h = np >> 2, g = np & 3;
    int src = (g * 512 + h) * 512 + k;
    dstX[idx] = f2bf(Wih[src]);
    dstH[idx] = f2bf(Whh[src]);
}

__global__ void conv_plain(unsigned short* dst, const float* __restrict__ src, int n) {
    int idx = blockIdx.x * 256 + threadIdx.x;
    if (idx < n) dst[idx] = f2bf(src[idx]);
}

// ---------------- xw precompute: xwb[s][b][n'] = emb[words]@Wx^T + bih + bhh ----------------
__global__ __launch_bounds__(256) void xw_kernel(
    const int* __restrict__ source, const int* __restrict__ target,
    const float* __restrict__ embS, const float* __restrict__ embT,
    const float* __restrict__ ebih, const float* __restrict__ ebhh,
    const float* __restrict__ dbih, const float* __restrict__ dbhh,
    const unsigned short* __restrict__ WxE, const unsigned short* __restrict__ WxD,
    unsigned short* __restrict__ xwb)
{
    __shared__ unsigned short xh[64 * 264];
    __shared__ int words_sm[64];
    const int s = blockIdx.x >> 5, sub = blockIdx.x & 31;
    const bool enc = (s < 128);
    const int col = enc ? s : (s - 128);
    const int* wsrc = enc ? source : target;
    const float* embed = enc ? embS : embT;
    const unsigned short* Wx = enc ? WxE : WxD;
    const float* b1 = enc ? ebih : dbih;
    const float* b2 = enc ? ebhh : dbhh;
    const int tid = threadIdx.x, lane = tid & 63, wave = tid >> 6;
    const int wm = wave >> 1, wn = wave & 1, l16 = lane & 15, lq = lane >> 4;
    const int n0 = sub * 64;
    if (tid < 64) words_sm[tid] = wsrc[tid * 128 + col];
    f32x4 acc[2][2] = {};
    for (int kt = 0; kt < 2; ++kt) {
        __syncthreads();
        for (int i = 0; i < 16; ++i) {
            int e4 = i * 256 + tid;
            int row = e4 >> 6, kloc = (e4 & 63) * 4;
            float4 v = *(const float4*)(embed + (long)words_sm[row] * 512 + kt * 256 + kloc);
            ushort4 sv;
            sv.x = f2bf(v.x); sv.y = f2bf(v.y); sv.z = f2bf(v.z); sv.w = f2bf(v.w);
            *(ushort4*)&xh[row * 264 + kloc] = sv;
        }
        __syncthreads();
        for (int ks = 0; ks < 8; ++ks) {
            bf16x8 a[2], b[2];
            for (int mt = 0; mt < 2; ++mt)
                a[mt] = *(const bf16x8*)&xh[(wm * 32 + mt * 16 + l16) * 264 + ks * 32 + lq * 8];
            for (int nt = 0; nt < 2; ++nt)
                b[nt] = *(const bf16x8*)(Wx + (long)(n0 + wn * 32 + nt * 16 + l16) * 512 + kt * 256 + ks * 32 + lq * 8);
            for (int mt = 0; mt < 2; ++mt)
                for (int nt = 0; nt < 2; ++nt)
                    acc[mt][nt] = __builtin_amdgcn_mfma_f32_16x16x32_bf16(a[mt], b[nt], acc[mt][nt], 0, 0, 0);
        }
    }
    for (int mt = 0; mt < 2; ++mt)
        for (int nt = 0; nt < 2; ++nt)
            for (int r = 0; r < 4; ++r) {
                int m = wm * 32 + mt * 16 + lq * 4 + r;
                int ng = n0 + wn * 32 + nt * 16 + l16;
                int bi = ((ng & 3) << 9) | (ng >> 2);
                float val = acc[mt][nt][r] + b1[bi] + b2[bi];
                xwb[((long)s * 64 + m) * 2048 + ng] = f2bf(val);
            }
}

// ---------------- LSTM recurrent phase (32 blocks), K=512 (h@Whh^T only) ----------------
__device__ void lstm_phase(int bid,
    const unsigned short* __restrict__ Wh,     // [2048][512] bf16 reordered
    const unsigned short* __restrict__ xwt,    // [64][2048] bf16, biases folded (sc1)
    const int* __restrict__ words,             // stride 128
    const unsigned short* __restrict__ hp,     // [64][512] bf16 or nullptr
    float* __restrict__ c_buf,                 // [64][512] f32 (block-private slice)
    unsigned short* __restrict__ h_out,        // [64][512] bf16
    char* smem_raw)
{
    unsigned short* xh    = (unsigned short*)smem_raw;            // [64][264]
    float* gsm            = (float*)(smem_raw + 33792);           // [64][65]
    int* words_sm         = (int*)(smem_raw + 50432);             // [64]
    unsigned short* hp_sm = (unsigned short*)(smem_raw + 50688);  // [64][16]
    unsigned short* xw_sm = (unsigned short*)(smem_raw + 52736);  // [64][68]
    const int tid = threadIdx.x, lane = tid & 63, wave = tid >> 6;
    const int wm = wave >> 1, wn = wave & 1, l16 = lane & 15, lq = lane >> 4;
    const int n0 = bid * 64, h0 = bid * 16;

    if (tid < 64) words_sm[tid] = words[tid * 128];

    // issue ALL staging up front: tA(8), tB(8), xw(2) per thread, via sc1
    ushort8 tA[8], tB[8], xwr[2];
    if (hp) {
        #pragma unroll
        for (int i = 0; i < 8; ++i) {
            int e8 = i * 256 + tid;
            LLC_LOAD8_ISSUE(tA[i], hp + (e8 >> 5) * 512 + (e8 & 31) * 8);
        }
        #pragma unroll
        for (int i = 0; i < 8; ++i) {
            int e8 = i * 256 + tid;
            LLC_LOAD8_ISSUE(tB[i], hp + (e8 >> 5) * 512 + 256 + (e8 & 31) * 8);
        }
    } else {
        #pragma unroll
        for (int i = 0; i < 8; ++i) { tA[i] = (ushort8)0; tB[i] = (ushort8)0; }
    }
    #pragma unroll
    for (int i = 0; i < 2; ++i) {
        int e8 = i * 256 + tid;
        LLC_LOAD8_ISSUE(xwr[i], xwt + (e8 >> 3) * 2048 + n0 + (e8 & 7) * 8);
    }
    WAITVM(10);    // tile0 (tA) complete; tB + xw still in flight
    #pragma unroll
    for (int i = 0; i < 8; ++i) {
        int e8 = i * 256 + tid;
        *(ushort8*)&xh[(e8 >> 5) * 264 + (e8 & 31) * 8] = tA[i];
    }
    __syncthreads();

    f32x4 acc[2][2] = {};
    #pragma unroll
    for (int ks = 0; ks < 8; ++ks) {
        bf16x8 a[2], b[2];
        for (int mt = 0; mt < 2; ++mt)
            a[mt] = *(const bf16x8*)&xh[(wm * 32 + mt * 16 + l16) * 264 + ks * 32 + lq * 8];
        for (int nt = 0; nt < 2; ++nt)
            b[nt] = *(const bf16x8*)(Wh + (long)(n0 + wn * 32 + nt * 16 + l16) * 512 + ks * 32 + lq * 8);
        for (int mt = 0; mt < 2; ++mt)
            for (int nt = 0; nt < 2; ++nt)
                acc[mt][nt] = __builtin_amdgcn_mfma_f32_16x16x32_bf16(a[mt], b[nt], acc[mt][nt], 0, 0, 0);
    }
    if (h0 < 256 && tid < 128)   // grab hp slice for mask path from tile0
        *(ushort8*)&hp_sm[(tid >> 1) * 16 + (tid & 1) * 8] =
            *(const ushort8*)&xh[(tid >> 1) * 264 + h0 + (tid & 1) * 8];
    __syncthreads();
    VMCNT0();      // tB + xw complete
    // park tile1 + xw tile
    #pragma unroll
    for (int i = 0; i < 8; ++i) {
        int e8 = i * 256 + tid;
        *(ushort8*)&xh[(e8 >> 5) * 264 + (e8 & 31) * 8] = tB[i];
    }
    #pragma unroll
    for (int i = 0; i < 2; ++i) {
        int e8 = i * 256 + tid;
        *(ushort8*)&xw_sm[(e8 >> 3) * 68 + (e8 & 7) * 8] = xwr[i];
    }
    __syncthreads();
    #pragma unroll
    for (int ks = 0; ks < 8; ++ks) {
        bf16x8 a[2], b[2];
        for (int mt = 0; mt < 2; ++mt)
            a[mt] = *(const bf16x8*)&xh[(wm * 32 + mt * 16 + l16) * 264 + ks * 32 + lq * 8];
        for (int nt = 0; nt < 2; ++nt)
            b[nt] = *(const bf16x8*)(Wh + (long)(n0 + wn * 32 + nt * 16 + l16) * 512 + 256 + ks * 32 + lq * 8);
        for (int mt = 0; mt < 2; ++mt)
            for (int nt = 0; nt < 2; ++nt)
                acc[mt][nt] = __builtin_amdgcn_mfma_f32_16x16x32_bf16(a[mt], b[nt], acc[mt][nt], 0, 0, 0);
    }
    if (h0 >= 256 && tid < 128)
        *(ushort8*)&hp_sm[(tid >> 1) * 16 + (tid & 1) * 8] =
            *(const ushort8*)&xh[(tid >> 1) * 264 + (h0 - 256) + (tid & 1) * 8];
    for (int mt = 0; mt < 2; ++mt)
        for (int nt = 0; nt < 2; ++nt)
            for (int r = 0; r < 4; ++r) {
                int m = wm * 32 + mt * 16 + lq * 4 + r;
                int n = wn * 32 + nt * 16 + l16;
                gsm[m * 65 + n] = acc[mt][nt][r];
            }
    __syncthreads();

    // epilogue: 2 h-columns per thread, packed stores
    for (int q = 0; q < 2; ++q) {
        int it = q * 256 + tid;            // 0..511
        int b = it >> 3, hl = (it & 7) * 2;
        int hg = h0 + hl;
        ushort4 xg0 = *(const ushort4*)&xw_sm[b * 68 + hl * 4];
        ushort4 xg1 = *(const ushort4*)&xw_sm[b * 68 + hl * 4 + 4];
        float i0 = gsm[b * 65 + hl * 4 + 0] + bf2f(xg0.x);
        float f0 = gsm[b * 65 + hl * 4 + 1] + bf2f(xg0.y);
        float g0 = gsm[b * 65 + hl * 4 + 2] + bf2f(xg0.z);
        float o0 = gsm[b * 65 + hl * 4 + 3] + bf2f(xg0.w);
        float i1 = gsm[b * 65 + hl * 4 + 4] + bf2f(xg1.x);
        float f1 = gsm[b * 65 + hl * 4 + 5] + bf2f(xg1.y);
        float g1 = gsm[b * 65 + hl * 4 + 6] + bf2f(xg1.z);
        float o1 = gsm[b * 65 + hl * 4 + 7] + bf2f(xg1.w);
        float c0old = c_buf[b * 512 + hg], c1old = c_buf[b * 512 + hg + 1];
        float c0 = (1.f / (1.f + __expf(-f0))) * c0old + (1.f / (1.f + __expf(-i0))) * tanhf(g0);
        float c1 = (1.f / (1.f + __expf(-f1))) * c1old + (1.f / (1.f + __expf(-i1))) * tanhf(g1);
        float h0v = (1.f / (1.f + __expf(-o0))) * tanhf(c0);
        float h1v = (1.f / (1.f + __expf(-o1))) * tanhf(c1);
        bool masked = (words_sm[b] == 0);
        unsigned short hb0 = masked ? hp_sm[b * 16 + hl]     : f2bf(h0v);
        unsigned short hb1 = masked ? hp_sm[b * 16 + hl + 1] : f2bf(h1v);
        float2 cw;
        cw.x = masked ? c0old : c0;
        cw.y = masked ? c1old : c1;
        *(float2*)&c_buf[b * 512 + hg] = cw;
        llc_store32(h_out + b * 512 + hg, (unsigned)hb0 | ((unsigned)hb1 << 16));
    }
}

// ---------------- attention phase (one block per batch column b) ----------------
__device__ void attn_phase(int b,
    const unsigned short* __restrict__ dh,      // [64][512] bf16 (sc1 read)
    const unsigned short* __restrict__ enc_hs,  // [128][64][512] bf16 (cached, static)
    const int* __restrict__ source,             // [64][128]
    unsigned short* __restrict__ ctx,           // [64][512] bf16 (sc1 write)
    char* smem_raw)
{
    float* h2s = (float*)smem_raw;            // [512]
    float* sc  = (float*)(smem_raw + 2048);   // [128]
    const int tid = threadIdx.x;
    if (tid < 64) {
        ushort8 v = llc_load8_wait(dh + b * 512 + tid * 8);
        #pragma unroll
        for (int j = 0; j < 8; ++j) h2s[tid * 8 + j] = bf2f(v[j]);
    }
    __syncthreads();
    const int wave = tid >> 6, lane = tid & 63;
    for (int i = 0; i < 32; ++i) {
        int tt = wave * 32 + i;
        ushort8 ev = *(const ushort8*)(enc_hs + ((long)tt * 64 + b) * 512 + lane * 8);
        const float* hq = h2s + lane * 8;
        float v = 0.f;
        #pragma unroll
        for (int j = 0; j < 8; ++j) v += bf2f(ev[j]) * hq[j];
        for (int off = 32; off; off >>= 1) v += __shfl_xor(v, off);
        if (lane == 0) sc[tt] = (source[b * 128 + tt] != 0) ? v : -1e30f;
    }
    __syncthreads();
    if (tid < 64) {
        float s0 = sc[tid], s1 = sc[tid + 64];
        float mx = fmaxf(s0, s1);
        for (int off = 32; off; off >>= 1) mx = fmaxf(mx, __shfl_xor(mx, off));
        float e0 = __expf(s0 - mx), e1 = __expf(s1 - mx);
        float sm = e0 + e1;
        for (int off = 32; off; off >>= 1) sm += __shfl_xor(sm, off);
        sc[tid] = e0 / sm;
        sc[tid + 64] = e1 / sm;
    }
    __syncthreads();
    float a0 = 0.f, a1 = 0.f;
    #pragma unroll 4
    for (int tt = 0; tt < 128; ++tt) {
        float w = sc[tt];
        unsigned pv = *(const unsigned*)(enc_hs + ((long)tt * 64 + b) * 512 + tid * 2);
        a0 += w * bf2f((unsigned short)(pv & 0xffff));
        a1 += w * bf2f((unsigned short)(pv >> 16));
    }
    unsigned pk = (unsigned)f2bf(a0) | ((unsigned)f2bf(a1) << 16);
    llc_store32(ctx + b * 512 + tid * 2, pk);
}

// ---------------- ha phase (8 blocks), register-double-buffered staging ----------------
#define HA_WRITE(reg) do { _Pragma("unroll") \
    for (int i = 0; i < 8; ++i) { int e8 = i * 256 + tid; \
        *(ushort8*)&xh[(e8 >> 5) * 264 + (e8 & 31) * 8] = reg[i]; } } while (0)
#define HA_ISSUE(reg, srcp, koff) do { _Pragma("unroll") \
    for (int i = 0; i < 8; ++i) { int e8 = i * 256 + tid; \
        LLC_LOAD8_ISSUE(reg[i], (srcp) + (e8 >> 5) * 512 + (koff) + (e8 & 31) * 8); } } while (0)
#define HA_MFMA(kt) do { _Pragma("unroll") \
    for (int ks = 0; ks < 8; ++ks) { \
        bf16x8 a[2], b[2]; \
        for (int mt = 0; mt < 2; ++mt) \
            a[mt] = *(const bf16x8*)&xh[(wm * 32 + mt * 16 + l16) * 264 + ks * 32 + lq * 8]; \
        for (int nt = 0; nt < 2; ++nt) \
            b[nt] = *(const bf16x8*)(Wa + (long)(n0 + wn * 32 + nt * 16 + l16) * 1024 + (kt) * 256 + ks * 32 + lq * 8); \
        for (int mt = 0; mt < 2; ++mt) \
            for (int nt = 0; nt < 2; ++nt) \
                acc[mt][nt] = __builtin_amdgcn_mfma_f32_16x16x32_bf16(a[mt], b[nt], acc[mt][nt], 0, 0, 0); \
    } } while (0)

__device__ void ha_phase(int bid,
    const unsigned short* __restrict__ ctx,  // [64][512] bf16 (sc1 read)
    const unsigned short* __restrict__ dh,   // [64][512] bf16 (sc1 read)
    const unsigned short* __restrict__ Wa,   // [512][1024] bf16 (cached, static)
    const float* __restrict__ ab,            // [512]
    unsigned short* __restrict__ ha,         // [64][512] bf16 (sc1 write)
    char* smem_raw)
{
    unsigned short* xh = (unsigned short*)smem_raw;   // [64][264]
    const int tid = threadIdx.x, lane = tid & 63, wave = tid >> 6;
    const int wm = wave >> 1, wn = wave & 1, l16 = lane & 15, lq = lane >> 4;
    const int n0 = bid * 64;
    f32x4 acc[2][2] = {};
    ushort8 rA[8], rB[8];
    HA_ISSUE(rA, ctx, 0);
    HA_ISSUE(rB, ctx, 256);
    VMCNT0();
    HA_WRITE(rA); __syncthreads();
    HA_ISSUE(rA, dh, 0);        // tile2 in flight during kt0
    HA_MFMA(0); __syncthreads();
    HA_WRITE(rB); __syncthreads();
    HA_ISSUE(rB, dh, 256);      // tile3 in flight during kt1
    HA_MFMA(1); __syncthreads();
    VMCNT0();
    HA_WRITE(rA); __syncthreads();
    HA_MFMA(2); __syncthreads();
    HA_WRITE(rB); __syncthreads();
    HA_MFMA(3);
    for (int mt = 0; mt < 2; ++mt)
        for (int nt = 0; nt < 2; ++nt)
            for (int r = 0; r < 4; ++r) {
                int m = wm * 32 + mt * 16 + lq * 4 + r;
                int n = n0 + wn * 32 + nt * 16 + l16;
                llc_store16(ha + m * 512 + n, f2bf(tanhf(acc[mt][nt][r] + ab[n])));
            }
}

// ---------------- logits phase (125 blocks) ----------------
__device__ void logits_phase(int bid, int tt,
    const unsigned short* __restrict__ ha,   // [64][512] bf16, fresh per t (cached)
    const unsigned short* __restrict__ Wo,   // [32000][512] bf16 (cached, static)
    const float* __restrict__ ob,            // [32000]
    const int* __restrict__ target,          // [64][128]
    float* __restrict__ sumexp,              // [127][64] (atomic)
    float* __restrict__ logit_t,             // [127][64] (sc1 write)
    char* smem_raw)
{
    float* se = (float*)smem_raw;    // [64]
    const int tid = threadIdx.x, lane = tid & 63, wave = tid >> 6;
    const int wm = wave >> 1, wn = wave & 1;
    const int l16 = lane & 15, lq = lane >> 4;
    const int n0 = bid * 256;
    f32x4 acc[2][8] = {};
    for (int ks = 0; ks < 16; ++ks) {
        bf16x8 a[2];
        for (int mt = 0; mt < 2; ++mt)
            a[mt] = *(const bf16x8*)(ha + (wm * 32 + mt * 16 + l16) * 512 + ks * 32 + lq * 8);
        for (int nt = 0; nt < 8; ++nt) {
            int v = n0 + wn * 128 + nt * 16 + l16;
            bf16x8 bb = *(const bf16x8*)(Wo + (long)v * 512 + ks * 32 + lq * 8);
            for (int mt = 0; mt < 2; ++mt)
                acc[mt][nt] = __builtin_amdgcn_mfma_f32_16x16x32_bf16(a[mt], bb, acc[mt][nt], 0, 0, 0);
        }
    }
    if (tid < 64) se[tid] = 0.f;
    __syncthreads();
    for (int mt = 0; mt < 2; ++mt) {
        for (int r = 0; r < 4; ++r) {
            int b = wm * 32 + mt * 16 + lq * 4 + r;
            int tw = target[b * 128 + tt + 1];
            float partial = 0.f;
            for (int nt = 0; nt < 8; ++nt) {
                int n = n0 + wn * 128 + nt * 16 + l16;
                float val = acc[mt][nt][r] + ob[n];
                partial += __expf(val);
                if (n == tw) llc_storef(logit_t + tt * 64 + b, val);
            }
            for (int m = 1; m < 16; m <<= 1) partial += __shfl_xor(partial, m);
            if (l16 == 0) atomicAdd(&se[b], partial);
        }
    }
    __syncthreads();
    if (tid < 64) atomicAdd(&sumexp[tt * 64 + tid], se[tid]);
}

// ---------------- loss phase (block 0) ----------------
__device__ void loss_phase(const float* __restrict__ sumexp,
                           const float* __restrict__ logit_t,
                           const int* __restrict__ target,
                           float* __restrict__ out,
                           char* smem_raw)
{
    float* red = (float*)smem_raw;   // [128]
    const int tid = threadIdx.x;
    float local = 0.f;
    if (tid < 127) {
        float s = 0.f; int cnt = 0;
        for (int b = 0; b < 64; ++b) {
            int w = target[b * 128 + tid + 1];
            if (w != 0) {
                s += logf(sumexp[tid * 64 + b]) - logit_t[tid * 64 + b];
                cnt++;
            }
        }
        int c = cnt > 1 ? cnt : 1;
        local = s / (float)c;
    }
    if (tid < 128) red[tid] = local;
    __syncthreads();
    if (tid == 0) {
        float tot = 0.f;
        for (int i = 0; i < 127; ++i) tot += red[i];
        out[0] = tot;
    }
}

// ---------------- persistent dataflow kernel ----------------
// roles: [0,32) lstm; [32,96) attn (1 col each); [96,104) ha; [104,229) logits.
__global__ __launch_bounds__(256) void seq_kernel(
    const int* __restrict__ source, const int* __restrict__ target,
    const float* __restrict__ attnb, const float* __restrict__ outb,
    const unsigned short* __restrict__ WhE, const unsigned short* __restrict__ WhD,
    const unsigned short* __restrict__ Wattn, const unsigned short* __restrict__ Wout,
    const unsigned short* __restrict__ xwb,
    unsigned short* enc_hs, unsigned short* dec_h, unsigned short* ctx,
    unsigned short* ha_t, float* c_buf, float* sumexp, float* logit_t,
    float* out, unsigned* flags)
{
    __shared__ __align__(16) char smem[61440];
    const int bid = blockIdx.x;
    const int tid = threadIdx.x;

    unsigned* flLstm = flags + FL_LSTM * 32;
    unsigned* flCtx  = flags + FL_CTX  * 32;
    unsigned* flHa   = flags + FL_HA   * 32;
    unsigned* dgr    = flags + FL_DGR  * 32;   // 8 decGen replicas
    unsigned* lgr    = flags + FL_LGR  * 32;   // 8 logGen replicas
    unsigned* logDone = flags + FL_LOGD * 32;

    if (bid < NLSTM) {
        // ---- LSTM lane: the serial recurrence. flag value = global step count ----
        int h0 = bid * 16;
        for (int q = 0; q < 4; ++q) {
            int it = q * 256 + tid;
            c_buf[(it & 63) * 512 + h0 + (it >> 6)] = 0.f;
        }
        for (int t = 0; t < 128; ++t) {
            if (t) {
                poll_flags(flLstm, 31, (unsigned)t);
                if (bid == 0 && tid < 8) llc_store32(&dgr[tid * 32], (unsigned)t);
            }
            lstm_phase(bid, WhE, xwb + (long)t * 131072, source + t,
                       t ? enc_hs + (long)(t - 1) * 32768 : nullptr,
                       c_buf, enc_hs + (long)t * 32768, smem);
            drain_sync();
            if (tid == 0) llc_store32(&flLstm[bid * 32], (unsigned)(t + 1));
        }
        for (int t = 0; t < 127; ++t) {
            poll_flags(flLstm, 31, (unsigned)(128 + t));
            if (bid == 0 && tid < 8) llc_store32(&dgr[tid * 32], (unsigned)(128 + t));
            lstm_phase(bid, WhD, xwb + (long)(128 + t) * 131072, target + t,
                       t ? dec_h + (long)(t - 1) * 32768 : enc_hs + (long)127 * 32768,
                       c_buf, dec_h + (long)t * 32768, smem);
            drain_sync();
            if (tid == 0) llc_store32(&flLstm[bid * 32], (unsigned)(129 + t));
        }
        if (bid == 0) {
            // publish the final step so attn can consume dec_h[126]
            poll_flags(flLstm, 31, 255u);
            if (tid < 8) llc_store32(&dgr[tid * 32], 255u);
            wait_count(logDone, (unsigned)NLOG);
            loss_phase(sumexp, logit_t, target, out, smem);
        }
    } else if (bid < ATTN0 + NATTN) {
        // ---- attention worker: one batch column; single-lane replica poll ----
        const int col = bid - ATTN0;
        const unsigned* myGen = &dgr[(bid & 7) * 32];
        for (int t = 0; t < 127; ++t) {
            poll_one(myGen, (unsigned)(129 + t));
            attn_phase(col, dec_h + (long)t * 32768, enc_hs, source,
                       ctx + (long)t * 32768, smem);
            drain_sync();
            if (tid == 0) llc_store32(&flCtx[col * 32], (unsigned)(t + 1));
        }
    } else if (bid < HA0 + NHA) {
        // ---- ha worker; worker 0 aggregates ha flags into logGen replicas ----
        const int sub = bid - HA0;
        for (int t = 0; t < 127; ++t) {
            poll_flags(flCtx, 63, (unsigned)(t + 1));
            ha_phase(sub, ctx + (long)t * 32768, dec_h + (long)t * 32768,
                     Wattn, attnb, ha_t + (long)t * 32768, smem);
            drain_sync();
            if (tid == 0) llc_store32(&flHa[sub * 32], (unsigned)(t + 1));
            if (sub == 0) {
                poll_flags(flHa, 7, (unsigned)(t + 1));
                if (tid < 8) llc_store32(&lgr[tid * 32], (unsigned)(t + 1));
            }
        }
    } else {
        // ---- logits worker: fixed vocab slice; single-lane replica poll ----
        const int sub = bid - LOG0;
        const unsigned* myGen = &lgr[(sub & 7) * 32];
        for (int t = 0; t < 127; ++t) {
            poll_one(myGen, (unsigned)(t + 1));
            logits_phase(sub, t, ha_t + (long)t * 32768, Wout, outb,
                         target, sumexp, logit_t, smem);
        }
        signal_count(logDone);
    }
}

// ---------------- host launcher ----------------
extern "C" void kernel_launch(void* const* d_in, const int* in_sizes, int n_in,
                              void* d_out, int out_size, void* d_ws, size_t ws_size,
                              hipStream_t stream)
{
    (void)in_sizes; (void)n_in; (void)out_size; (void)ws_size;
    const int*   source = (const int*)  d_in[0];
    const int*   target = (const int*)  d_in[1];
    const float* embS   = (const float*)d_in[2];
    const float* embT   = (const float*)d_in[3];
    const float* eWih   = (const float*)d_in[4];
    const float* eWhh   = (const float*)d_in[5];
    const float* ebih   = (const float*)d_in[6];
    const float* ebhh   = (const float*)d_in[7];
    const float* dWih   = (const float*)d_in[8];
    const float* dWhh   = (const float*)d_in[9];
    const float* dbih   = (const float*)d_in[10];
    const float* dbhh   = (const float*)d_in[11];
    const float* attnW  = (const float*)d_in[12];
    const float* attnb  = (const float*)d_in[13];
    const float* outW   = (const float*)d_in[14];
    const float* outb   = (const float*)d_in[15];
    float* out = (float*)d_out;
    char* ws = (char*)d_ws;

    // layout (dec_h/ctx overlap the encoder half of xwb: encoder xwb is consumed
    // strictly before decoder writes, and ALL accesses on both sides are sc1)
    unsigned short* enc_hs = (unsigned short*)(ws);               //  8,388,608
    unsigned short* ha_t   = (unsigned short*)(ws + 8388608);     //  8,388,608
    unsigned short* xwb    = (unsigned short*)(ws + 16777216);    // 66,846,720
    unsigned short* dec_h  = (unsigned short*)(ws + 16777216);    //  8,323,072 (overlap)
    unsigned short* ctx    = (unsigned short*)(ws + 25100288);    //  8,323,072 (overlap)
    float* c_buf           = (float*)(ws + 83623936);             //    131,072
    float* sumexp          = (float*)(ws + 83755008);             //     32,768
    float* logitt          = (float*)(ws + 83787776);             //     32,768
    unsigned short* WxE    = (unsigned short*)(ws + 83820544);    //  2,097,152
    unsigned short* WhE    = (unsigned short*)(ws + 85917696);    //  2,097,152
    unsigned short* WxD    = (unsigned short*)(ws + 88014848);    //  2,097,152
    unsigned short* WhD    = (unsigned short*)(ws + 90112000);    //  2,097,152
    unsigned short* Wattn  = (unsigned short*)(ws + 92209152);    //  1,048,576
    unsigned short* Wout   = (unsigned short*)(ws + 93257728);    // 32,768,000
    unsigned* flags        = (unsigned*)(ws + 126025728);         //     16,384

    hipMemsetAsync(flags, 0, 16384, stream);
    hipMemsetAsync(sumexp, 0, 32768, stream);
    conv_lstm_w2<<<4096, 256, 0, stream>>>(WxE, WhE, eWih, eWhh);
    conv_lstm_w2<<<4096, 256, 0, stream>>>(WxD, WhD, dWih, dWhh);
    conv_plain<<<2048, 256, 0, stream>>>(Wattn, attnW, 512 * 1024);
    conv_plain<<<64000, 256, 0, stream>>>(Wout, outW, 32000 * 512);
    xw_kernel<<<255 * 32, 256, 0, stream>>>(source, target, embS, embT,
                                            ebih, ebhh, dbih, dbhh, WxE, WxD, xwb);

    seq_kernel<<<NBLK, 256, 0, stream>>>(
        source, target, attnb, outb,
        WhE, WhD, Wattn, Wout, xwb,
        enc_hs, dec_h, ctx, ha_t, c_buf, sumexp, logitt,
        out, flags);
}

// Round 11
// 4194.392 us; speedup vs baseline: 1.1854x; 1.1854x over previous
//
#include <hip/hip_runtime.h>
#include <hip/hip_bf16.h>
#include <math.h>

typedef __attribute__((ext_vector_type(8))) short bf16x8;
typedef __attribute__((ext_vector_type(8))) unsigned short ushort8;
typedef __attribute__((ext_vector_type(4))) float f32x4;

// block roles
#define NLSTM 32
#define ATTN0 32
#define NATTN 64
#define HA0   96
#define NHA   8
#define LOG0  104
#define NLOG  125
#define NBLK  229

static __device__ inline unsigned short f2bf(float f) {
    unsigned u = __builtin_bit_cast(unsigned, f);
    u += 0x7fffu + ((u >> 16) & 1u);   // RNE
    return (unsigned short)(u >> 16);
}
static __device__ inline float bf2f(unsigned short u) {
    return __builtin_bit_cast(float, ((unsigned)u) << 16);
}

// ---- LLC-coherent (L1/L2-bypassing) access helpers: no cache maintenance ----
__device__ inline ushort8 llc_load8_wait(const unsigned short* p) {
    ushort8 v;
    asm volatile("global_load_dwordx4 %0, %1, off sc0 sc1\n\ts_waitcnt vmcnt(0)"
                 : "=v"(v) : "v"(p) : "memory");
    return v;
}
#define LLC_LOAD8_ISSUE(dst, p) \
    asm volatile("global_load_dwordx4 %0, %1, off sc0 sc1" : "=v"(dst) : "v"(p))
#define VMCNT0() do { asm volatile("s_waitcnt vmcnt(0)" ::: "memory"); \
                      __builtin_amdgcn_sched_barrier(0); } while (0)
#define WAITVM(N) do { asm volatile("s_waitcnt vmcnt(" #N ")" ::: "memory"); \
                       __builtin_amdgcn_sched_barrier(0); } while (0)
__device__ inline void llc_store16(unsigned short* p, unsigned short v) {
    unsigned uv = v;
    asm volatile("global_store_short %0, %1, off sc0 sc1" :: "v"(p), "v"(uv) : "memory");
}
__device__ inline void llc_store32(void* p, unsigned v) {
    asm volatile("global_store_dword %0, %1, off sc0 sc1" :: "v"(p), "v"(v) : "memory");
}
__device__ inline void llc_storef(float* p, float v) {
    asm volatile("global_store_dword %0, %1, off sc0 sc1" :: "v"(p), "v"(__builtin_bit_cast(unsigned, v)) : "memory");
}

// non-temporal (no L2 allocate) streaming load — compiler handles waitcnt/sched
__device__ inline bf16x8 nt_load8(const unsigned short* p) {
    return __builtin_nontemporal_load((const bf16x8*)p);
}

// ---------------- sync primitives (round-8 proven) ----------------
__device__ inline void lstm_bar(unsigned* arr, unsigned* gen, unsigned target) {
    asm volatile("s_waitcnt vmcnt(0)" ::: "memory");   // drain own sc1 stores
    __syncthreads();
    if (threadIdx.x == 0) {
        if (__hip_atomic_fetch_add(arr, 1u, __ATOMIC_RELAXED, __HIP_MEMORY_SCOPE_AGENT)
            == target * (unsigned)NLSTM - 1u) {
            __hip_atomic_store(gen, target, __ATOMIC_RELAXED, __HIP_MEMORY_SCOPE_AGENT);
        } else {
            while (__hip_atomic_load(gen, __ATOMIC_RELAXED, __HIP_MEMORY_SCOPE_AGENT) < target)
                __builtin_amdgcn_s_sleep(2);
        }
    }
    __syncthreads();
}

__device__ inline void wait_flag(unsigned* f, unsigned target) {
    if (threadIdx.x == 0) {
        while (__hip_atomic_load(f, __ATOMIC_RELAXED, __HIP_MEMORY_SCOPE_AGENT) < target)
            __builtin_amdgcn_s_sleep(4);
    }
    __syncthreads();
}

__device__ inline void signal_done(unsigned* f) {
    asm volatile("s_waitcnt vmcnt(0)" ::: "memory");   // data (sc1/atomic) drained first
    __syncthreads();
    if (threadIdx.x == 0)
        __hip_atomic_fetch_add(f, 1u, __ATOMIC_RELAXED, __HIP_MEMORY_SCOPE_AGENT);
}

// ---------------- one-time conversion kernels ----------------

__global__ void conv_lstm_w2(unsigned short* dstX, unsigned short* dstH,
                             const float* __restrict__ Wih,
                             const float* __restrict__ Whh) {
    int idx = blockIdx.x * 256 + threadIdx.x;      // < 2048*512
    int np = idx >> 9, k = idx & 511;
    int h = np >> 2, g = np & 3;
    int src = (g * 512 + h) * 512 + k;
    dstX[idx] = f2bf(Wih[src]);
    dstH[idx] = f2bf(Whh[src]);
}

__global__ void conv_plain(unsigned short* dst, const float* __restrict__ src, int n) {
    int idx = blockIdx.x * 256 + threadIdx.x;
    if (idx < n) dst[idx] = f2bf(src[idx]);
}

// ---------------- xw precompute: xwb[s][b][n'] = emb[words]@Wx^T + bih + bhh ----------------
__global__ __launch_bounds__(256) void xw_kernel(
    const int* __restrict__ source, const int* __restrict__ target,
    const float* __restrict__ embS, const float* __restrict__ embT,
    const float* __restrict__ ebih, const float* __restrict__ ebhh,
    const float* __restrict__ dbih, const float* __restrict__ dbhh,
    const unsigned short* __restrict__ WxE, const unsigned short* __restrict__ WxD,
    unsigned short* __restrict__ xwb)
{
    __shared__ unsigned short xh[64 * 264];
    __shared__ int words_sm[64];
    const int s = blockIdx.x >> 5, sub = blockIdx.x & 31;
    const bool enc = (s < 128);
    const int col = enc ? s : (s - 128);
    const int* wsrc = enc ? source : target;
    const float* embed = enc ? embS : embT;
    const unsigned short* Wx = enc ? WxE : WxD;
    const float* b1 = enc ? ebih : dbih;
    const float* b2 = enc ? ebhh : dbhh;
    const int tid = threadIdx.x, lane = tid & 63, wave = tid >> 6;
    const int wm = wave >> 1, wn = wave & 1, l16 = lane & 15, lq = lane >> 4;
    const int n0 = sub * 64;
    if (tid < 64) words_sm[tid] = wsrc[tid * 128 + col];
    f32x4 acc[2][2] = {};
    for (int kt = 0; kt < 2; ++kt) {
        __syncthreads();
        for (int i = 0; i < 16; ++i) {
            int e4 = i * 256 + tid;
            int row = e4 >> 6, kloc = (e4 & 63) * 4;
            float4 v = *(const float4*)(embed + (long)words_sm[row] * 512 + kt * 256 + kloc);
            ushort4 sv;
            sv.x = f2bf(v.x); sv.y = f2bf(v.y); sv.z = f2bf(v.z); sv.w = f2bf(v.w);
            *(ushort4*)&xh[row * 264 + kloc] = sv;
        }
        __syncthreads();
        for (int ks = 0; ks < 8; ++ks) {
            bf16x8 a[2], b[2];
            for (int mt = 0; mt < 2; ++mt)
                a[mt] = *(const bf16x8*)&xh[(wm * 32 + mt * 16 + l16) * 264 + ks * 32 + lq * 8];
            for (int nt = 0; nt < 2; ++nt)
                b[nt] = *(const bf16x8*)(Wx + (long)(n0 + wn * 32 + nt * 16 + l16) * 512 + kt * 256 + ks * 32 + lq * 8);
            for (int mt = 0; mt < 2; ++mt)
                for (int nt = 0; nt < 2; ++nt)
                    acc[mt][nt] = __builtin_amdgcn_mfma_f32_16x16x32_bf16(a[mt], b[nt], acc[mt][nt], 0, 0, 0);
        }
    }
    for (int mt = 0; mt < 2; ++mt)
        for (int nt = 0; nt < 2; ++nt)
            for (int r = 0; r < 4; ++r) {
                int m = wm * 32 + mt * 16 + lq * 4 + r;
                int ng = n0 + wn * 32 + nt * 16 + l16;
                int bi = ((ng & 3) << 9) | (ng >> 2);
                float val = acc[mt][nt][r] + b1[bi] + b2[bi];
                xwb[((long)s * 64 + m) * 2048 + ng] = f2bf(val);
            }
}

// ---------------- LSTM recurrent phase (32 blocks), K=512 (h@Whh^T only) ----------------
__device__ void lstm_phase(int bid,
    const unsigned short* __restrict__ Wh,     // [2048][512] bf16 reordered (plain, L2-hot)
    const unsigned short* __restrict__ xwt,    // [64][2048] bf16, biases folded (sc1)
    const int* __restrict__ words,             // stride 128
    const unsigned short* __restrict__ hp,     // [64][512] bf16 or nullptr
    float* __restrict__ c_buf,                 // [64][512] f32 (block-private slice)
    unsigned short* __restrict__ h_out,        // [64][512] bf16
    char* smem_raw)
{
    unsigned short* xh    = (unsigned short*)smem_raw;            // [64][264]
    float* gsm            = (float*)(smem_raw + 33792);           // [64][65]
    int* words_sm         = (int*)(smem_raw + 50432);             // [64]
    unsigned short* hp_sm = (unsigned short*)(smem_raw + 50688);  // [64][16]
    unsigned short* xw_sm = (unsigned short*)(smem_raw + 52736);  // [64][68]
    const int tid = threadIdx.x, lane = tid & 63, wave = tid >> 6;
    const int wm = wave >> 1, wn = wave & 1, l16 = lane & 15, lq = lane >> 4;
    const int n0 = bid * 64, h0 = bid * 16;

    if (tid < 64) words_sm[tid] = words[tid * 128];

    // issue ALL staging up front: tA(8), tB(8), xw(2) per thread, via sc1
    ushort8 tA[8], tB[8], xwr[2];
    if (hp) {
        #pragma unroll
        for (int i = 0; i < 8; ++i) {
            int e8 = i * 256 + tid;
            LLC_LOAD8_ISSUE(tA[i], hp + (e8 >> 5) * 512 + (e8 & 31) * 8);
        }
        #pragma unroll
        for (int i = 0; i < 8; ++i) {
            int e8 = i * 256 + tid;
            LLC_LOAD8_ISSUE(tB[i], hp + (e8 >> 5) * 512 + 256 + (e8 & 31) * 8);
        }
    } else {
        #pragma unroll
        for (int i = 0; i < 8; ++i) { tA[i] = (ushort8)0; tB[i] = (ushort8)0; }
    }
    #pragma unroll
    for (int i = 0; i < 2; ++i) {
        int e8 = i * 256 + tid;
        LLC_LOAD8_ISSUE(xwr[i], xwt + (e8 >> 3) * 2048 + n0 + (e8 & 7) * 8);
    }
    WAITVM(10);    // tile0 (tA) complete; tB + xw still in flight
    #pragma unroll
    for (int i = 0; i < 8; ++i) {
        int e8 = i * 256 + tid;
        *(ushort8*)&xh[(e8 >> 5) * 264 + (e8 & 31) * 8] = tA[i];
    }
    __syncthreads();

    f32x4 acc[2][2] = {};
    #pragma unroll
    for (int ks = 0; ks < 8; ++ks) {
        bf16x8 a[2], b[2];
        for (int mt = 0; mt < 2; ++mt)
            a[mt] = *(const bf16x8*)&xh[(wm * 32 + mt * 16 + l16) * 264 + ks * 32 + lq * 8];
        for (int nt = 0; nt < 2; ++nt)
            b[nt] = *(const bf16x8*)(Wh + (long)(n0 + wn * 32 + nt * 16 + l16) * 512 + ks * 32 + lq * 8);
        for (int mt = 0; mt < 2; ++mt)
            for (int nt = 0; nt < 2; ++nt)
                acc[mt][nt] = __builtin_amdgcn_mfma_f32_16x16x32_bf16(a[mt], b[nt], acc[mt][nt], 0, 0, 0);
    }
    if (h0 < 256 && tid < 128)   // grab hp slice for mask path from tile0
        *(ushort8*)&hp_sm[(tid >> 1) * 16 + (tid & 1) * 8] =
            *(const ushort8*)&xh[(tid >> 1) * 264 + h0 + (tid & 1) * 8];
    __syncthreads();
    VMCNT0();      // tB + xw complete
    #pragma unroll
    for (int i = 0; i < 8; ++i) {
        int e8 = i * 256 + tid;
        *(ushort8*)&xh[(e8 >> 5) * 264 + (e8 & 31) * 8] = tB[i];
    }
    #pragma unroll
    for (int i = 0; i < 2; ++i) {
        int e8 = i * 256 + tid;
        *(ushort8*)&xw_sm[(e8 >> 3) * 68 + (e8 & 7) * 8] = xwr[i];
    }
    __syncthreads();
    #pragma unroll
    for (int ks = 0; ks < 8; ++ks) {
        bf16x8 a[2], b[2];
        for (int mt = 0; mt < 2; ++mt)
            a[mt] = *(const bf16x8*)&xh[(wm * 32 + mt * 16 + l16) * 264 + ks * 32 + lq * 8];
        for (int nt = 0; nt < 2; ++nt)
            b[nt] = *(const bf16x8*)(Wh + (long)(n0 + wn * 32 + nt * 16 + l16) * 512 + 256 + ks * 32 + lq * 8);
        for (int mt = 0; mt < 2; ++mt)
            for (int nt = 0; nt < 2; ++nt)
                acc[mt][nt] = __builtin_amdgcn_mfma_f32_16x16x32_bf16(a[mt], b[nt], acc[mt][nt], 0, 0, 0);
    }
    if (h0 >= 256 && tid < 128)
        *(ushort8*)&hp_sm[(tid >> 1) * 16 + (tid & 1) * 8] =
            *(const ushort8*)&xh[(tid >> 1) * 264 + (h0 - 256) + (tid & 1) * 8];
    for (int mt = 0; mt < 2; ++mt)
        for (int nt = 0; nt < 2; ++nt)
            for (int r = 0; r < 4; ++r) {
                int m = wm * 32 + mt * 16 + lq * 4 + r;
                int n = wn * 32 + nt * 16 + l16;
                gsm[m * 65 + n] = acc[mt][nt][r];
            }
    __syncthreads();

    // epilogue: 2 h-columns per thread, packed stores
    for (int q = 0; q < 2; ++q) {
        int it = q * 256 + tid;            // 0..511
        int b = it >> 3, hl = (it & 7) * 2;
        int hg = h0 + hl;
        ushort4 xg0 = *(const ushort4*)&xw_sm[b * 68 + hl * 4];
        ushort4 xg1 = *(const ushort4*)&xw_sm[b * 68 + hl * 4 + 4];
        float i0 = gsm[b * 65 + hl * 4 + 0] + bf2f(xg0.x);
        float f0 = gsm[b * 65 + hl * 4 + 1] + bf2f(xg0.y);
        float g0 = gsm[b * 65 + hl * 4 + 2] + bf2f(xg0.z);
        float o0 = gsm[b * 65 + hl * 4 + 3] + bf2f(xg0.w);
        float i1 = gsm[b * 65 + hl * 4 + 4] + bf2f(xg1.x);
        float f1 = gsm[b * 65 + hl * 4 + 5] + bf2f(xg1.y);
        float g1 = gsm[b * 65 + hl * 4 + 6] + bf2f(xg1.z);
        float o1 = gsm[b * 65 + hl * 4 + 7] + bf2f(xg1.w);
        float c0old = c_buf[b * 512 + hg], c1old = c_buf[b * 512 + hg + 1];
        float c0 = (1.f / (1.f + __expf(-f0))) * c0old + (1.f / (1.f + __expf(-i0))) * tanhf(g0);
        float c1 = (1.f / (1.f + __expf(-f1))) * c1old + (1.f / (1.f + __expf(-i1))) * tanhf(g1);
        float h0v = (1.f / (1.f + __expf(-o0))) * tanhf(c0);
        float h1v = (1.f / (1.f + __expf(-o1))) * tanhf(c1);
        bool masked = (words_sm[b] == 0);
        unsigned short hb0 = masked ? hp_sm[b * 16 + hl]     : f2bf(h0v);
        unsigned short hb1 = masked ? hp_sm[b * 16 + hl + 1] : f2bf(h1v);
        float2 cw;
        cw.x = masked ? c0old : c0;
        cw.y = masked ? c1old : c1;
        *(float2*)&c_buf[b * 512 + hg] = cw;
        llc_store32(h_out + b * 512 + hg, (unsigned)hb0 | ((unsigned)hb1 << 16));
    }
}

// ---------------- attention phase (one block per batch column b) ----------------
__device__ void attn_phase(int b,
    const unsigned short* __restrict__ dh,      // [64][512] bf16 (sc1 read)
    const unsigned short* __restrict__ enc_hs,  // [128][64][512] bf16 (plain, L2-hot slice)
    const int* __restrict__ source,             // [64][128]
    unsigned short* __restrict__ ctx,           // [64][512] bf16 (sc1 write)
    char* smem_raw)
{
    float* h2s = (float*)smem_raw;            // [512]
    float* sc  = (float*)(smem_raw + 2048);   // [128]
    const int tid = threadIdx.x;
    if (tid < 64) {
        ushort8 v = llc_load8_wait(dh + b * 512 + tid * 8);
        #pragma unroll
        for (int j = 0; j < 8; ++j) h2s[tid * 8 + j] = bf2f(v[j]);
    }
    __syncthreads();
    const int wave = tid >> 6, lane = tid & 63;
    for (int i = 0; i < 32; ++i) {
        int tt = wave * 32 + i;
        ushort8 ev = *(const ushort8*)(enc_hs + ((long)tt * 64 + b) * 512 + lane * 8);
        const float* hq = h2s + lane * 8;
        float v = 0.f;
        #pragma unroll
        for (int j = 0; j < 8; ++j) v += bf2f(ev[j]) * hq[j];
        for (int off = 32; off; off >>= 1) v += __shfl_xor(v, off);
        if (lane == 0) sc[tt] = (source[b * 128 + tt] != 0) ? v : -1e30f;
    }
    __syncthreads();
    if (tid < 64) {
        float s0 = sc[tid], s1 = sc[tid + 64];
        float mx = fmaxf(s0, s1);
        for (int off = 32; off; off >>= 1) mx = fmaxf(mx, __shfl_xor(mx, off));
        float e0 = __expf(s0 - mx), e1 = __expf(s1 - mx);
        float sm = e0 + e1;
        for (int off = 32; off; off >>= 1) sm += __shfl_xor(sm, off);
        sc[tid] = e0 / sm;
        sc[tid + 64] = e1 / sm;
    }
    __syncthreads();
    float a0 = 0.f, a1 = 0.f;
    #pragma unroll 4
    for (int tt = 0; tt < 128; ++tt) {
        float w = sc[tt];
        unsigned pv = *(const unsigned*)(enc_hs + ((long)tt * 64 + b) * 512 + tid * 2);
        a0 += w * bf2f((unsigned short)(pv & 0xffff));
        a1 += w * bf2f((unsigned short)(pv >> 16));
    }
    unsigned pk = (unsigned)f2bf(a0) | ((unsigned)f2bf(a1) << 16);
    llc_store32(ctx + b * 512 + tid * 2, pk);
}

// ---------------- ha phase (8 blocks), register-double-buffered staging ----------------
#define HA_WRITE(reg) do { _Pragma("unroll") \
    for (int i = 0; i < 8; ++i) { int e8 = i * 256 + tid; \
        *(ushort8*)&xh[(e8 >> 5) * 264 + (e8 & 31) * 8] = reg[i]; } } while (0)
#define HA_ISSUE(reg, srcp, koff) do { _Pragma("unroll") \
    for (int i = 0; i < 8; ++i) { int e8 = i * 256 + tid; \
        LLC_LOAD8_ISSUE(reg[i], (srcp) + (e8 >> 5) * 512 + (koff) + (e8 & 31) * 8); } } while (0)
#define HA_MFMA(kt) do { _Pragma("unroll") \
    for (int ks = 0; ks < 8; ++ks) { \
        bf16x8 a[2], b[2]; \
        for (int mt = 0; mt < 2; ++mt) \
            a[mt] = *(const bf16x8*)&xh[(wm * 32 + mt * 16 + l16) * 264 + ks * 32 + lq * 8]; \
        for (int nt = 0; nt < 2; ++nt) \
            b[nt] = *(const bf16x8*)(Wa + (long)(n0 + wn * 32 + nt * 16 + l16) * 1024 + (kt) * 256 + ks * 32 + lq * 8); \
        for (int mt = 0; mt < 2; ++mt) \
            for (int nt = 0; nt < 2; ++nt) \
                acc[mt][nt] = __builtin_amdgcn_mfma_f32_16x16x32_bf16(a[mt], b[nt], acc[mt][nt], 0, 0, 0); \
    } } while (0)

__device__ void ha_phase(int bid,
    const unsigned short* __restrict__ ctx,  // [64][512] bf16 (sc1 read)
    const unsigned short* __restrict__ dh,   // [64][512] bf16 (sc1 read)
    const unsigned short* __restrict__ Wa,   // [512][1024] bf16 (plain, L2-hot)
    const float* __restrict__ ab,            // [512]
    unsigned short* __restrict__ ha,         // [64][512] bf16 (sc1 write)
    char* smem_raw)
{
    unsigned short* xh = (unsigned short*)smem_raw;   // [64][264]
    const int tid = threadIdx.x, lane = tid & 63, wave = tid >> 6;
    const int wm = wave >> 1, wn = wave & 1, l16 = lane & 15, lq = lane >> 4;
    const int n0 = bid * 64;
    f32x4 acc[2][2] = {};
    ushort8 rA[8], rB[8];
    HA_ISSUE(rA, ctx, 0);
    HA_ISSUE(rB, ctx, 256);
    VMCNT0();
    HA_WRITE(rA); __syncthreads();
    HA_ISSUE(rA, dh, 0);        // tile2 in flight during kt0
    HA_MFMA(0); __syncthreads();
    HA_WRITE(rB); __syncthreads();
    HA_ISSUE(rB, dh, 256);      // tile3 in flight during kt1
    HA_MFMA(1); __syncthreads();
    VMCNT0();
    HA_WRITE(rA); __syncthreads();
    HA_MFMA(2); __syncthreads();
    HA_WRITE(rB); __syncthreads();
    HA_MFMA(3);
    for (int mt = 0; mt < 2; ++mt)
        for (int nt = 0; nt < 2; ++nt)
            for (int r = 0; r < 4; ++r) {
                int m = wm * 32 + mt * 16 + lq * 4 + r;
                int n = n0 + wn * 32 + nt * 16 + l16;
                llc_store16(ha + m * 512 + n, f2bf(tanhf(acc[mt][nt][r] + ab[n])));
            }
}

// ---------------- logits phase (125 blocks) — NT streaming loads ----------------
__device__ void logits_phase(int bid, int tt,
    const unsigned short* __restrict__ ha,   // [64][512] bf16 (nt read: no L2 pollution)
    const unsigned short* __restrict__ Wo,   // [32000][512] bf16 (nt read: no L2 pollution)
    const float* __restrict__ ob,            // [32000]
    const int* __restrict__ target,          // [64][128]
    float* __restrict__ sumexp,              // [127][64] (atomic)
    float* __restrict__ logit_t,             // [127][64] (sc1 write)
    char* smem_raw)
{
    float* se = (float*)smem_raw;    // [64]
    const int tid = threadIdx.x, lane = tid & 63, wave = tid >> 6;
    const int wm = wave >> 1, wn = wave & 1;
    const int l16 = lane & 15, lq = lane >> 4;
    const int n0 = bid * 256;
    f32x4 acc[2][8] = {};
    for (int ks = 0; ks < 16; ++ks) {
        bf16x8 a[2];
        for (int mt = 0; mt < 2; ++mt)
            a[mt] = nt_load8(ha + (wm * 32 + mt * 16 + l16) * 512 + ks * 32 + lq * 8);
        for (int nt = 0; nt < 8; ++nt) {
            int v = n0 + wn * 128 + nt * 16 + l16;
            bf16x8 bb = nt_load8(Wo + (long)v * 512 + ks * 32 + lq * 8);
            for (int mt = 0; mt < 2; ++mt)
                acc[mt][nt] = __builtin_amdgcn_mfma_f32_16x16x32_bf16(a[mt], bb, acc[mt][nt], 0, 0, 0);
        }
    }
    if (tid < 64) se[tid] = 0.f;
    __syncthreads();
    for (int mt = 0; mt < 2; ++mt) {
        for (int r = 0; r < 4; ++r) {
            int b = wm * 32 + mt * 16 + lq * 4 + r;
            int tw = target[b * 128 + tt + 1];
            float partial = 0.f;
            for (int nt = 0; nt < 8; ++nt) {
                int n = n0 + wn * 128 + nt * 16 + l16;
                float val = acc[mt][nt][r] + ob[n];
                partial += __expf(val);
                if (n == tw) llc_storef(logit_t + tt * 64 + b, val);
            }
            for (int m = 1; m < 16; m <<= 1) partial += __shfl_xor(partial, m);
            if (l16 == 0) atomicAdd(&se[b], partial);
        }
    }
    __syncthreads();
    if (tid < 64) atomicAdd(&sumexp[tt * 64 + tid], se[tid]);
}

// ---------------- loss phase (block 0) ----------------
__device__ void loss_phase(const float* __restrict__ sumexp,
                           const float* __restrict__ logit_t,
                           const int* __restrict__ target,
                           float* __restrict__ out,
                           char* smem_raw)
{
    float* red = (float*)smem_raw;   // [128]
    const int tid = threadIdx.x;
    float local = 0.f;
    if (tid < 127) {
        float s = 0.f; int cnt = 0;
        for (int b = 0; b < 64; ++b) {
            int w = target[b * 128 + tid + 1];
            if (w != 0) {
                s += logf(sumexp[tid * 64 + b]) - logit_t[tid * 64 + b];
                cnt++;
            }
        }
        int c = cnt > 1 ? cnt : 1;
        local = s / (float)c;
    }
    if (tid < 128) red[tid] = local;
    __syncthreads();
    if (tid == 0) {
        float tot = 0.f;
        for (int i = 0; i < 127; ++i) tot += red[i];
        out[0] = tot;
    }
}

// ---------------- persistent dataflow kernel (round-8 sync topology) ----------------
// roles: [0,32) lstm; [32,96) attn (1 col each); [96,104) ha; [104,229) logits.
// flags (128B-padded u32): 0 encArr, 1 encGen, 2 decArr, 3 decGen, 4 logitsDone,
//                          [5..132) ctxReady[t], [132..259) haReady[t]
__global__ __launch_bounds__(256) void seq_kernel(
    const int* __restrict__ source, const int* __restrict__ target,
    const float* __restrict__ attnb, const float* __restrict__ outb,
    const unsigned short* __restrict__ WhE, const unsigned short* __restrict__ WhD,
    const unsigned short* __restrict__ Wattn, const unsigned short* __restrict__ Wout,
    const unsigned short* __restrict__ xwb,
    unsigned short* enc_hs, unsigned short* dec_h, unsigned short* ctx,
    unsigned short* ha_t, float* c_buf, float* sumexp, float* logit_t,
    float* out, unsigned* flags)
{
    __shared__ __align__(16) char smem[61440];
    const int bid = blockIdx.x;
    const int tid = threadIdx.x;

    unsigned* encArr = flags + 0 * 32;
    unsigned* encGen = flags + 1 * 32;
    unsigned* decArr = flags + 2 * 32;
    unsigned* decGen = flags + 3 * 32;
    unsigned* logDone = flags + 4 * 32;
    unsigned* ctxReady = flags + 5 * 32;           // [t]*32
    unsigned* haReady  = flags + (5 + 127) * 32;   // [t]*32

    if (bid < NLSTM) {
        // ---- LSTM lane: zero private c slice, then encoder + decoder recurrence ----
        int h0 = bid * 16;
        for (int q = 0; q < 4; ++q) {
            int it = q * 256 + tid;
            c_buf[(it & 63) * 512 + h0 + (it >> 6)] = 0.f;
        }
        for (int t = 0; t < 128; ++t) {
            lstm_phase(bid, WhE, xwb + (long)t * 131072, source + t,
                       t ? enc_hs + (long)(t - 1) * 32768 : nullptr,
                       c_buf, enc_hs + (long)t * 32768, smem);
            lstm_bar(encArr, encGen, (unsigned)(t + 1));
        }
        for (int t = 0; t < 127; ++t) {
            lstm_phase(bid, WhD, xwb + (long)(128 + t) * 131072, target + t,
                       t ? dec_h + (long)(t - 1) * 32768 : enc_hs + (long)127 * 32768,
                       c_buf, dec_h + (long)t * 32768, smem);
            lstm_bar(decArr, decGen, (unsigned)(t + 1));
        }
        if (bid == 0) {
            wait_flag(logDone, (unsigned)NLOG);
            loss_phase(sumexp, logit_t, target, out, smem);
        }
    } else if (bid < ATTN0 + NATTN) {
        // ---- attention worker: one batch column, consumes dec_h[t] as it appears ----
        const int col = bid - ATTN0;
        for (int t = 0; t < 127; ++t) {
            wait_flag(decGen, (unsigned)(t + 1));
            attn_phase(col, dec_h + (long)t * 32768, enc_hs, source,
                       ctx + (long)t * 32768, smem);
            signal_done(&ctxReady[t * 32]);
        }
    } else if (bid < HA0 + NHA) {
        // ---- ha worker ----
        const int sub = bid - HA0;
        for (int t = 0; t < 127; ++t) {
            wait_flag(&ctxReady[t * 32], (unsigned)NATTN);
            ha_phase(sub, ctx + (long)t * 32768, dec_h + (long)t * 32768,
                     Wattn, attnb, ha_t + (long)t * 32768, smem);
            signal_done(&haReady[t * 32]);
        }
    } else {
        // ---- logits worker: fixed vocab slice, streams all t ----
        const int sub = bid - LOG0;
        for (int t = 0; t < 127; ++t) {
            wait_flag(&haReady[t * 32], (unsigned)NHA);
            logits_phase(sub, t, ha_t + (long)t * 32768, Wout, outb,
                         target, sumexp, logit_t, smem);
        }
        signal_done(logDone);
    }
}

// ---------------- host launcher ----------------
extern "C" void kernel_launch(void* const* d_in, const int* in_sizes, int n_in,
                              void* d_out, int out_size, void* d_ws, size_t ws_size,
                              hipStream_t stream)
{
    (void)in_sizes; (void)n_in; (void)out_size; (void)ws_size;
    const int*   source = (const int*)  d_in[0];
    const int*   target = (const int*)  d_in[1];
    const float* embS   = (const float*)d_in[2];
    const float* embT   = (const float*)d_in[3];
    const float* eWih   = (const float*)d_in[4];
    const float* eWhh   = (const float*)d_in[5];
    const float* ebih   = (const float*)d_in[6];
    const float* ebhh   = (const float*)d_in[7];
    const float* dWih   = (const float*)d_in[8];
    const float* dWhh   = (const float*)d_in[9];
    const float* dbih   = (const float*)d_in[10];
    const float* dbhh   = (const float*)d_in[11];
    const float* attnW  = (const float*)d_in[12];
    const float* attnb  = (const float*)d_in[13];
    const float* outW   = (const float*)d_in[14];
    const float* outb   = (const float*)d_in[15];
    float* out = (float*)d_out;
    char* ws = (char*)d_ws;

    // layout (dec_h/ctx overlap the encoder half of xwb: encoder xwb is consumed
    // strictly before decoder writes, and ALL accesses on both sides are sc1)
    unsigned short* enc_hs = (unsigned short*)(ws);               //  8,388,608
    unsigned short* ha_t   = (unsigned short*)(ws + 8388608);     //  8,388,608
    unsigned short* xwb    = (unsigned short*)(ws + 16777216);    // 66,846,720
    unsigned short* dec_h  = (unsigned short*)(ws + 16777216);    //  8,323,072 (overlap)
    unsigned short* ctx    = (unsigned short*)(ws + 25100288);    //  8,323,072 (overlap)
    float* c_buf           = (float*)(ws + 83623936);             //    131,072
    float* sumexp          = (float*)(ws + 83755008);             //     32,768
    float* logitt          = (float*)(ws + 83787776);             //     32,768
    unsigned short* WxE    = (unsigned short*)(ws + 83820544);    //  2,097,152
    unsigned short* WhE    = (unsigned short*)(ws + 85917696);    //  2,097,152
    unsigned short* WxD    = (unsigned short*)(ws + 88014848);    //  2,097,152
    unsigned short* WhD    = (unsigned short*)(ws + 90112000);    //  2,097,152
    unsigned short* Wattn  = (unsigned short*)(ws + 92209152);    //  1,048,576
    unsigned short* Wout   = (unsigned short*)(ws + 93257728);    // 32,768,000
    unsigned* flags        = (unsigned*)(ws + 126025728);         //     33,280

    hipMemsetAsync(flags, 0, 33280, stream);
    hipMemsetAsync(sumexp, 0, 32768, stream);
    conv_lstm_w2<<<4096, 256, 0, stream>>>(WxE, WhE, eWih, eWhh);
    conv_lstm_w2<<<4096, 256, 0, stream>>>(WxD, WhD, dWih, dWhh);
    conv_plain<<<2048, 256, 0, stream>>>(Wattn, attnW, 512 * 1024);
    conv_plain<<<64000, 256, 0, stream>>>(Wout, outW, 32000 * 512);
    xw_kernel<<<255 * 32, 256, 0, stream>>>(source, target, embS, embT,
                                            ebih, ebhh, dbih, dbhh, WxE, WxD, xwb);

    seq_kernel<<<NBLK, 256, 0, stream>>>(
        source, target, attnb, outb,
        WhE, WhD, Wattn, Wout, xwb,
        enc_hs, dec_h, ctx, ha_t, c_buf, sumexp, logitt,
        out, flags);
}

// Round 12
// 4101.110 us; speedup vs baseline: 1.2124x; 1.0227x over previous
//
#include <hip/hip_runtime.h>
#include <hip/hip_bf16.h>
#include <math.h>

typedef __attribute__((ext_vector_type(8))) short bf16x8;
typedef __attribute__((ext_vector_type(8))) unsigned short ushort8;
typedef __attribute__((ext_vector_type(4))) float f32x4;

// block roles
#define NLSTM 32
#define ATTN0 32
#define NATTN 64
#define HA0   96
#define NHA   8
#define LOG0  104
#define NLOG  125
#define NBLK  229

static __device__ inline unsigned short f2bf(float f) {
    unsigned u = __builtin_bit_cast(unsigned, f);
    u += 0x7fffu + ((u >> 16) & 1u);   // RNE
    return (unsigned short)(u >> 16);
}
static __device__ inline float bf2f(unsigned short u) {
    return __builtin_bit_cast(float, ((unsigned)u) << 16);
}

// ---- LLC-coherent (L1/L2-bypassing) access helpers: no cache maintenance ----
__device__ inline ushort8 llc_load8_wait(const unsigned short* p) {
    ushort8 v;
    asm volatile("global_load_dwordx4 %0, %1, off sc0 sc1\n\ts_waitcnt vmcnt(0)"
                 : "=v"(v) : "v"(p) : "memory");
    return v;
}
#define LLC_LOAD8_ISSUE(dst, p) \
    asm volatile("global_load_dwordx4 %0, %1, off sc0 sc1" : "=v"(dst) : "v"(p))
#define VMCNT0() do { asm volatile("s_waitcnt vmcnt(0)" ::: "memory"); \
                      __builtin_amdgcn_sched_barrier(0); } while (0)
#define WAITVM(N) do { asm volatile("s_waitcnt vmcnt(" #N ")" ::: "memory"); \
                       __builtin_amdgcn_sched_barrier(0); } while (0)
__device__ inline void llc_store16(unsigned short* p, unsigned short v) {
    unsigned uv = v;
    asm volatile("global_store_short %0, %1, off sc0 sc1" :: "v"(p), "v"(uv) : "memory");
}
__device__ inline void llc_store32(void* p, unsigned v) {
    asm volatile("global_store_dword %0, %1, off sc0 sc1" :: "v"(p), "v"(v) : "memory");
}
__device__ inline void llc_storef(float* p, float v) {
    asm volatile("global_store_dword %0, %1, off sc0 sc1" :: "v"(p), "v"(__builtin_bit_cast(unsigned, v)) : "memory");
}

// ---------------- flag arena: 4KB-page-scattered lines (distinct LLC slices) ----------------
// page0: encArr@0, encGen@2048 ; page1: decArr ; page2: decGen ; page3: logDone
// pages [8,24): ctxReady[t] at page 8+(t&15), line (t>>4)*128
// pages [24,40): haReady[t]  at page 24+(t&15), line (t>>4)*128
#define FLAGS_ARENA_BYTES (40 * 4096)
__device__ inline unsigned* fl_enc_arr(unsigned* f) { return f; }
__device__ inline unsigned* fl_enc_gen(unsigned* f) { return f + 2048 / 4; }
__device__ inline unsigned* fl_dec_arr(unsigned* f) { return f + 4096 / 4; }
__device__ inline unsigned* fl_dec_gen(unsigned* f) { return f + 2 * 4096 / 4; }
__device__ inline unsigned* fl_log_done(unsigned* f) { return f + 3 * 4096 / 4; }
__device__ inline unsigned* fl_ctx_ready(unsigned* f, int t) {
    return f + ((8 + (t & 15)) * 4096 + (t >> 4) * 128) / 4;
}
__device__ inline unsigned* fl_ha_ready(unsigned* f, int t) {
    return f + ((24 + (t & 15)) * 4096 + (t >> 4) * 128) / 4;
}

// ---------------- sync primitives ----------------
// LSTM barrier (critical path): round-8 proven, tight poll
__device__ inline void lstm_bar(unsigned* arr, unsigned* gen, unsigned target) {
    asm volatile("s_waitcnt vmcnt(0)" ::: "memory");   // drain own sc1 stores
    __syncthreads();
    if (threadIdx.x == 0) {
        if (__hip_atomic_fetch_add(arr, 1u, __ATOMIC_RELAXED, __HIP_MEMORY_SCOPE_AGENT)
            == target * (unsigned)NLSTM - 1u) {
            __hip_atomic_store(gen, target, __ATOMIC_RELAXED, __HIP_MEMORY_SCOPE_AGENT);
        } else {
            while (__hip_atomic_load(gen, __ATOMIC_RELAXED, __HIP_MEMORY_SCOPE_AGENT) < target)
                __builtin_amdgcn_s_sleep(2);
        }
    }
    __syncthreads();
}

// downstream pollers (off critical path): progressive backoff, cap ~1.7us
__device__ inline void wait_flag_bo(unsigned* f, unsigned target) {
    if (threadIdx.x == 0) {
        int c = 0;
        while (__hip_atomic_load(f, __ATOMIC_RELAXED, __HIP_MEMORY_SCOPE_AGENT) < target) {
            if (c < 8) __builtin_amdgcn_s_sleep(2);
            else if (c < 16) __builtin_amdgcn_s_sleep(16);
            else __builtin_amdgcn_s_sleep(64);
            ++c;
        }
    }
    __syncthreads();
}

__device__ inline void signal_done(unsigned* f) {
    asm volatile("s_waitcnt vmcnt(0)" ::: "memory");   // data (sc1/atomic) drained first
    __syncthreads();
    if (threadIdx.x == 0)
        __hip_atomic_fetch_add(f, 1u, __ATOMIC_RELAXED, __HIP_MEMORY_SCOPE_AGENT);
}

// ---------------- one-time conversion kernels ----------------

__global__ void conv_lstm_w2(unsigned short* dstX, unsigned short* dstH,
                             const float* __restrict__ Wih,
                             const float* __restrict__ Whh) {
    int idx = blockIdx.x * 256 + threadIdx.x;      // < 2048*512
    int np = idx >> 9, k = idx & 511;
    int h = np >> 2, g = np & 3;
    int src = (g * 512 + h) * 512 + k;
    dstX[idx] = f2bf(Wih[src]);
    dstH[idx] = f2bf(Whh[src]);
}

__global__ void conv_plain(unsigned short* dst, const float* __restrict__ src, int n) {
    int idx = blockIdx.x * 256 + threadIdx.x;
    if (idx < n) dst[idx] = f2bf(src[idx]);
}

// ---------------- xw precompute: xwb[s][b][n'] = emb[words]@Wx^T + bih + bhh ----------------
__global__ __launch_bounds__(256) void xw_kernel(
    const int* __restrict__ source, const int* __restrict__ target,
    const float* __restrict__ embS, const float* __restrict__ embT,
    const float* __restrict__ ebih, const float* __restrict__ ebhh,
    const float* __restrict__ dbih, const float* __restrict__ dbhh,
    const unsigned short* __restrict__ WxE, const unsigned short* __restrict__ WxD,
    unsigned short* __restrict__ xwb)
{
    __shared__ unsigned short xh[64 * 264];
    __shared__ int words_sm[64];
    const int s = blockIdx.x >> 5, sub = blockIdx.x & 31;
    const bool enc = (s < 128);
    const int col = enc ? s : (s - 128);
    const int* wsrc = enc ? source : target;
    const float* embed = enc ? embS : embT;
    const unsigned short* Wx = enc ? WxE : WxD;
    const float* b1 = enc ? ebih : dbih;
    const float* b2 = enc ? ebhh : dbhh;
    const int tid = threadIdx.x, lane = tid & 63, wave = tid >> 6;
    const int wm = wave >> 1, wn = wave & 1, l16 = lane & 15, lq = lane >> 4;
    const int n0 = sub * 64;
    if (tid < 64) words_sm[tid] = wsrc[tid * 128 + col];
    f32x4 acc[2][2] = {};
    for (int kt = 0; kt < 2; ++kt) {
        __syncthreads();
        for (int i = 0; i < 16; ++i) {
            int e4 = i * 256 + tid;
            int row = e4 >> 6, kloc = (e4 & 63) * 4;
            float4 v = *(const float4*)(embed + (long)words_sm[row] * 512 + kt * 256 + kloc);
            ushort4 sv;
            sv.x = f2bf(v.x); sv.y = f2bf(v.y); sv.z = f2bf(v.z); sv.w = f2bf(v.w);
            *(ushort4*)&xh[row * 264 + kloc] = sv;
        }
        __syncthreads();
        for (int ks = 0; ks < 8; ++ks) {
            bf16x8 a[2], b[2];
            for (int mt = 0; mt < 2; ++mt)
                a[mt] = *(const bf16x8*)&xh[(wm * 32 + mt * 16 + l16) * 264 + ks * 32 + lq * 8];
            for (int nt = 0; nt < 2; ++nt)
                b[nt] = *(const bf16x8*)(Wx + (long)(n0 + wn * 32 + nt * 16 + l16) * 512 + kt * 256 + ks * 32 + lq * 8);
            for (int mt = 0; mt < 2; ++mt)
                for (int nt = 0; nt < 2; ++nt)
                    acc[mt][nt] = __builtin_amdgcn_mfma_f32_16x16x32_bf16(a[mt], b[nt], acc[mt][nt], 0, 0, 0);
        }
    }
    for (int mt = 0; mt < 2; ++mt)
        for (int nt = 0; nt < 2; ++nt)
            for (int r = 0; r < 4; ++r) {
                int m = wm * 32 + mt * 16 + lq * 4 + r;
                int ng = n0 + wn * 32 + nt * 16 + l16;
                int bi = ((ng & 3) << 9) | (ng >> 2);
                float val = acc[mt][nt][r] + b1[bi] + b2[bi];
                xwb[((long)s * 64 + m) * 2048 + ng] = f2bf(val);
            }
}

// ---------------- LSTM recurrent phase (32 blocks), K=512 (h@Whh^T only) ----------------
__device__ void lstm_phase(int bid,
    const unsigned short* __restrict__ Wh,     // [2048][512] bf16 reordered (plain, L2-hot)
    const unsigned short* __restrict__ xwt,    // [64][2048] bf16, biases folded (sc1)
    const int* __restrict__ words,             // stride 128
    const unsigned short* __restrict__ hp,     // [64][512] bf16 or nullptr
    float* __restrict__ c_buf,                 // [64][512] f32 (block-private slice)
    unsigned short* __restrict__ h_out,        // [64][512] bf16
    char* smem_raw)
{
    unsigned short* xh    = (unsigned short*)smem_raw;            // [64][264]
    float* gsm            = (float*)(smem_raw + 33792);           // [64][65]
    int* words_sm         = (int*)(smem_raw + 50432);             // [64]
    unsigned short* hp_sm = (unsigned short*)(smem_raw + 50688);  // [64][16]
    unsigned short* xw_sm = (unsigned short*)(smem_raw + 52736);  // [64][68]
    const int tid = threadIdx.x, lane = tid & 63, wave = tid >> 6;
    const int wm = wave >> 1, wn = wave & 1, l16 = lane & 15, lq = lane >> 4;
    const int n0 = bid * 64, h0 = bid * 16;

    if (tid < 64) words_sm[tid] = words[tid * 128];

    // issue ALL staging up front: tA(8), tB(8), xw(2) per thread, via sc1
    ushort8 tA[8], tB[8], xwr[2];
    if (hp) {
        #pragma unroll
        for (int i = 0; i < 8; ++i) {
            int e8 = i * 256 + tid;
            LLC_LOAD8_ISSUE(tA[i], hp + (e8 >> 5) * 512 + (e8 & 31) * 8);
        }
        #pragma unroll
        for (int i = 0; i < 8; ++i) {
            int e8 = i * 256 + tid;
            LLC_LOAD8_ISSUE(tB[i], hp + (e8 >> 5) * 512 + 256 + (e8 & 31) * 8);
        }
    } else {
        #pragma unroll
        for (int i = 0; i < 8; ++i) { tA[i] = (ushort8)0; tB[i] = (ushort8)0; }
    }
    #pragma unroll
    for (int i = 0; i < 2; ++i) {
        int e8 = i * 256 + tid;
        LLC_LOAD8_ISSUE(xwr[i], xwt + (e8 >> 3) * 2048 + n0 + (e8 & 7) * 8);
    }
    WAITVM(10);    // tile0 (tA) complete; tB + xw still in flight
    #pragma unroll
    for (int i = 0; i < 8; ++i) {
        int e8 = i * 256 + tid;
        *(ushort8*)&xh[(e8 >> 5) * 264 + (e8 & 31) * 8] = tA[i];
    }
    __syncthreads();

    f32x4 acc[2][2] = {};
    #pragma unroll
    for (int ks = 0; ks < 8; ++ks) {
        bf16x8 a[2], b[2];
        for (int mt = 0; mt < 2; ++mt)
            a[mt] = *(const bf16x8*)&xh[(wm * 32 + mt * 16 + l16) * 264 + ks * 32 + lq * 8];
        for (int nt = 0; nt < 2; ++nt)
            b[nt] = *(const bf16x8*)(Wh + (long)(n0 + wn * 32 + nt * 16 + l16) * 512 + ks * 32 + lq * 8);
        for (int mt = 0; mt < 2; ++mt)
            for (int nt = 0; nt < 2; ++nt)
                acc[mt][nt] = __builtin_amdgcn_mfma_f32_16x16x32_bf16(a[mt], b[nt], acc[mt][nt], 0, 0, 0);
    }
    if (h0 < 256 && tid < 128)   // grab hp slice for mask path from tile0
        *(ushort8*)&hp_sm[(tid >> 1) * 16 + (tid & 1) * 8] =
            *(const ushort8*)&xh[(tid >> 1) * 264 + h0 + (tid & 1) * 8];
    __syncthreads();
    VMCNT0();      // tB + xw complete
    #pragma unroll
    for (int i = 0; i < 8; ++i) {
        int e8 = i * 256 + tid;
        *(ushort8*)&xh[(e8 >> 5) * 264 + (e8 & 31) * 8] = tB[i];
    }
    #pragma unroll
    for (int i = 0; i < 2; ++i) {
        int e8 = i * 256 + tid;
        *(ushort8*)&xw_sm[(e8 >> 3) * 68 + (e8 & 7) * 8] = xwr[i];
    }
    __syncthreads();
    #pragma unroll
    for (int ks = 0; ks < 8; ++ks) {
        bf16x8 a[2], b[2];
        for (int mt = 0; mt < 2; ++mt)
            a[mt] = *(const bf16x8*)&xh[(wm * 32 + mt * 16 + l16) * 264 + ks * 32 + lq * 8];
        for (int nt = 0; nt < 2; ++nt)
            b[nt] = *(const bf16x8*)(Wh + (long)(n0 + wn * 32 + nt * 16 + l16) * 512 + 256 + ks * 32 + lq * 8);
        for (int mt = 0; mt < 2; ++mt)
            for (int nt = 0; nt < 2; ++nt)
                acc[mt][nt] = __builtin_amdgcn_mfma_f32_16x16x32_bf16(a[mt], b[nt], acc[mt][nt], 0, 0, 0);
    }
    if (h0 >= 256 && tid < 128)
        *(ushort8*)&hp_sm[(tid >> 1) * 16 + (tid & 1) * 8] =
            *(const ushort8*)&xh[(tid >> 1) * 264 + (h0 - 256) + (tid & 1) * 8];
    for (int mt = 0; mt < 2; ++mt)
        for (int nt = 0; nt < 2; ++nt)
            for (int r = 0; r < 4; ++r) {
                int m = wm * 32 + mt * 16 + lq * 4 + r;
                int n = wn * 32 + nt * 16 + l16;
                gsm[m * 65 + n] = acc[mt][nt][r];
            }
    __syncthreads();

    // epilogue: 2 h-columns per thread, packed stores
    for (int q = 0; q < 2; ++q) {
        int it = q * 256 + tid;            // 0..511
        int b = it >> 3, hl = (it & 7) * 2;
        int hg = h0 + hl;
        ushort4 xg0 = *(const ushort4*)&xw_sm[b * 68 + hl * 4];
        ushort4 xg1 = *(const ushort4*)&xw_sm[b * 68 + hl * 4 + 4];
        float i0 = gsm[b * 65 + hl * 4 + 0] + bf2f(xg0.x);
        float f0 = gsm[b * 65 + hl * 4 + 1] + bf2f(xg0.y);
        float g0 = gsm[b * 65 + hl * 4 + 2] + bf2f(xg0.z);
        float o0 = gsm[b * 65 + hl * 4 + 3] + bf2f(xg0.w);
        float i1 = gsm[b * 65 + hl * 4 + 4] + bf2f(xg1.x);
        float f1 = gsm[b * 65 + hl * 4 + 5] + bf2f(xg1.y);
        float g1 = gsm[b * 65 + hl * 4 + 6] + bf2f(xg1.z);
        float o1 = gsm[b * 65 + hl * 4 + 7] + bf2f(xg1.w);
        float c0old = c_buf[b * 512 + hg], c1old = c_buf[b * 512 + hg + 1];
        float c0 = (1.f / (1.f + __expf(-f0))) * c0old + (1.f / (1.f + __expf(-i0))) * tanhf(g0);
        float c1 = (1.f / (1.f + __expf(-f1))) * c1old + (1.f / (1.f + __expf(-i1))) * tanhf(g1);
        float h0v = (1.f / (1.f + __expf(-o0))) * tanhf(c0);
        float h1v = (1.f / (1.f + __expf(-o1))) * tanhf(c1);
        bool masked = (words_sm[b] == 0);
        unsigned short hb0 = masked ? hp_sm[b * 16 + hl]     : f2bf(h0v);
        unsigned short hb1 = masked ? hp_sm[b * 16 + hl + 1] : f2bf(h1v);
        float2 cw;
        cw.x = masked ? c0old : c0;
        cw.y = masked ? c1old : c1;
        *(float2*)&c_buf[b * 512 + hg] = cw;
        llc_store32(h_out + b * 512 + hg, (unsigned)hb0 | ((unsigned)hb1 << 16));
    }
}

// ---------------- attention phase (one block per batch column b) ----------------
__device__ void attn_phase(int b,
    const unsigned short* __restrict__ dh,      // [64][512] bf16 (sc1 read)
    const unsigned short* __restrict__ enc_hs,  // [128][64][512] bf16 (plain, L2-hot slice)
    const int* __restrict__ source,             // [64][128]
    unsigned short* __restrict__ ctx,           // [64][512] bf16 (sc1 write)
    char* smem_raw)
{
    float* h2s = (float*)smem_raw;            // [512]
    float* sc  = (float*)(smem_raw + 2048);   // [128]
    const int tid = threadIdx.x;
    if (tid < 64) {
        ushort8 v = llc_load8_wait(dh + b * 512 + tid * 8);
        #pragma unroll
        for (int j = 0; j < 8; ++j) h2s[tid * 8 + j] = bf2f(v[j]);
    }
    __syncthreads();
    const int wave = tid >> 6, lane = tid & 63;
    for (int i = 0; i < 32; ++i) {
        int tt = wave * 32 + i;
        ushort8 ev = *(const ushort8*)(enc_hs + ((long)tt * 64 + b) * 512 + lane * 8);
        const float* hq = h2s + lane * 8;
        float v = 0.f;
        #pragma unroll
        for (int j = 0; j < 8; ++j) v += bf2f(ev[j]) * hq[j];
        for (int off = 32; off; off >>= 1) v += __shfl_xor(v, off);
        if (lane == 0) sc[tt] = (source[b * 128 + tt] != 0) ? v : -1e30f;
    }
    __syncthreads();
    if (tid < 64) {
        float s0 = sc[tid], s1 = sc[tid + 64];
        float mx = fmaxf(s0, s1);
        for (int off = 32; off; off >>= 1) mx = fmaxf(mx, __shfl_xor(mx, off));
        float e0 = __expf(s0 - mx), e1 = __expf(s1 - mx);
        float sm = e0 + e1;
        for (int off = 32; off; off >>= 1) sm += __shfl_xor(sm, off);
        sc[tid] = e0 / sm;
        sc[tid + 64] = e1 / sm;
    }
    __syncthreads();
    float a0 = 0.f, a1 = 0.f;
    #pragma unroll 4
    for (int tt = 0; tt < 128; ++tt) {
        float w = sc[tt];
        unsigned pv = *(const unsigned*)(enc_hs + ((long)tt * 64 + b) * 512 + tid * 2);
        a0 += w * bf2f((unsigned short)(pv & 0xffff));
        a1 += w * bf2f((unsigned short)(pv >> 16));
    }
    unsigned pk = (unsigned)f2bf(a0) | ((unsigned)f2bf(a1) << 16);
    llc_store32(ctx + b * 512 + tid * 2, pk);
}

// ---------------- ha phase (8 blocks), register-double-buffered staging ----------------
#define HA_WRITE(reg) do { _Pragma("unroll") \
    for (int i = 0; i < 8; ++i) { int e8 = i * 256 + tid; \
        *(ushort8*)&xh[(e8 >> 5) * 264 + (e8 & 31) * 8] = reg[i]; } } while (0)
#define HA_ISSUE(reg, srcp, koff) do { _Pragma("unroll") \
    for (int i = 0; i < 8; ++i) { int e8 = i * 256 + tid; \
        LLC_LOAD8_ISSUE(reg[i], (srcp) + (e8 >> 5) * 512 + (koff) + (e8 & 31) * 8); } } while (0)
#define HA_MFMA(kt) do { _Pragma("unroll") \
    for (int ks = 0; ks < 8; ++ks) { \
        bf16x8 a[2], b[2]; \
        for (int mt = 0; mt < 2; ++mt) \
            a[mt] = *(const bf16x8*)&xh[(wm * 32 + mt * 16 + l16) * 264 + ks * 32 + lq * 8]; \
        for (int nt = 0; nt < 2; ++nt) \
            b[nt] = *(const bf16x8*)(Wa + (long)(n0 + wn * 32 + nt * 16 + l16) * 1024 + (kt) * 256 + ks * 32 + lq * 8); \
        for (int mt = 0; mt < 2; ++mt) \
            for (int nt = 0; nt < 2; ++nt) \
                acc[mt][nt] = __builtin_amdgcn_mfma_f32_16x16x32_bf16(a[mt], b[nt], acc[mt][nt], 0, 0, 0); \
    } } while (0)

__device__ void ha_phase(int bid,
    const unsigned short* __restrict__ ctx,  // [64][512] bf16 (sc1 read)
    const unsigned short* __restrict__ dh,   // [64][512] bf16 (sc1 read)
    const unsigned short* __restrict__ Wa,   // [512][1024] bf16 (plain, L2-hot)
    const float* __restrict__ ab,            // [512]
    unsigned short* __restrict__ ha,         // [64][512] bf16 (sc1 write)
    char* smem_raw)
{
    unsigned short* xh = (unsigned short*)smem_raw;   // [64][264]
    const int tid = threadIdx.x, lane = tid & 63, wave = tid >> 6;
    const int wm = wave >> 1, wn = wave & 1, l16 = lane & 15, lq = lane >> 4;
    const int n0 = bid * 64;
    f32x4 acc[2][2] = {};
    ushort8 rA[8], rB[8];
    HA_ISSUE(rA, ctx, 0);
    HA_ISSUE(rB, ctx, 256);
    VMCNT0();
    HA_WRITE(rA); __syncthreads();
    HA_ISSUE(rA, dh, 0);        // tile2 in flight during kt0
    HA_MFMA(0); __syncthreads();
    HA_WRITE(rB); __syncthreads();
    HA_ISSUE(rB, dh, 256);      // tile3 in flight during kt1
    HA_MFMA(1); __syncthreads();
    VMCNT0();
    HA_WRITE(rA); __syncthreads();
    HA_MFMA(2); __syncthreads();
    HA_WRITE(rB); __syncthreads();
    HA_MFMA(3);
    for (int mt = 0; mt < 2; ++mt)
        for (int nt = 0; nt < 2; ++nt)
            for (int r = 0; r < 4; ++r) {
                int m = wm * 32 + mt * 16 + lq * 4 + r;
                int n = n0 + wn * 32 + nt * 16 + l16;
                llc_store16(ha + m * 512 + n, f2bf(tanhf(acc[mt][nt][r] + ab[n])));
            }
}

// ---------------- logits phase (125 blocks) ----------------
__device__ void logits_phase(int bid, int tt,
    const unsigned short* __restrict__ ha,   // [64][512] bf16, fresh per t (cached)
    const unsigned short* __restrict__ Wo,   // [32000][512] bf16 (cached, static)
    const float* __restrict__ ob,            // [32000]
    const int* __restrict__ target,          // [64][128]
    float* __restrict__ sumexp,              // [127][64] (atomic)
    float* __restrict__ logit_t,             // [127][64] (sc1 write)
    char* smem_raw)
{
    float* se = (float*)smem_raw;    // [64]
    const int tid = threadIdx.x, lane = tid & 63, wave = tid >> 6;
    const int wm = wave >> 1, wn = wave & 1;
    const int l16 = lane & 15, lq = lane >> 4;
    const int n0 = bid * 256;
    f32x4 acc[2][8] = {};
    for (int ks = 0; ks < 16; ++ks) {
        bf16x8 a[2];
        for (int mt = 0; mt < 2; ++mt)
            a[mt] = *(const bf16x8*)(ha + (wm * 32 + mt * 16 + l16) * 512 + ks * 32 + lq * 8);
        for (int nt = 0; nt < 8; ++nt) {
            int v = n0 + wn * 128 + nt * 16 + l16;
            bf16x8 bb = *(const bf16x8*)(Wo + (long)v * 512 + ks * 32 + lq * 8);
            for (int mt = 0; mt < 2; ++mt)
                acc[mt][nt] = __builtin_amdgcn_mfma_f32_16x16x32_bf16(a[mt], bb, acc[mt][nt], 0, 0, 0);
        }
    }
    if (tid < 64) se[tid] = 0.f;
    __syncthreads();
    for (int mt = 0; mt < 2; ++mt) {
        for (int r = 0; r < 4; ++r) {
            int b = wm * 32 + mt * 16 + lq * 4 + r;
            int tw = target[b * 128 + tt + 1];
            float partial = 0.f;
            for (int nt = 0; nt < 8; ++nt) {
                int n = n0 + wn * 128 + nt * 16 + l16;
                float val = acc[mt][nt][r] + ob[n];
                partial += __expf(val);
                if (n == tw) llc_storef(logit_t + tt * 64 + b, val);
            }
            for (int m = 1; m < 16; m <<= 1) partial += __shfl_xor(partial, m);
            if (l16 == 0) atomicAdd(&se[b], partial);
        }
    }
    __syncthreads();
    if (tid < 64) atomicAdd(&sumexp[tt * 64 + tid], se[tid]);
}

// ---------------- loss phase (block 0) ----------------
__device__ void loss_phase(const float* __restrict__ sumexp,
                           const float* __restrict__ logit_t,
                           const int* __restrict__ target,
                           float* __restrict__ out,
                           char* smem_raw)
{
    float* red = (float*)smem_raw;   // [128]
    const int tid = threadIdx.x;
    float local = 0.f;
    if (tid < 127) {
        float s = 0.f; int cnt = 0;
        for (int b = 0; b < 64; ++b) {
            int w = target[b * 128 + tid + 1];
            if (w != 0) {
                s += logf(sumexp[tid * 64 + b]) - logit_t[tid * 64 + b];
                cnt++;
            }
        }
        int c = cnt > 1 ? cnt : 1;
        local = s / (float)c;
    }
    if (tid < 128) red[tid] = local;
    __syncthreads();
    if (tid == 0) {
        float tot = 0.f;
        for (int i = 0; i < 127; ++i) tot += red[i];
        out[0] = tot;
    }
}

// ---------------- persistent dataflow kernel (round-8 topology, quiet pollers) ----------------
// roles: [0,32) lstm; [32,96) attn (1 col each); [96,104) ha; [104,229) logits.
__global__ __launch_bounds__(256) void seq_kernel(
    const int* __restrict__ source, const int* __restrict__ target,
    const float* __restrict__ attnb, const float* __restrict__ outb,
    const unsigned short* __restrict__ WhE, const unsigned short* __restrict__ WhD,
    const unsigned short* __restrict__ Wattn, const unsigned short* __restrict__ Wout,
    const unsigned short* __restrict__ xwb,
    unsigned short* enc_hs, unsigned short* dec_h, unsigned short* ctx,
    unsigned short* ha_t, float* c_buf, float* sumexp, float* logit_t,
    float* out, unsigned* flags)
{
    __shared__ __align__(16) char smem[61440];
    const int bid = blockIdx.x;
    const int tid = threadIdx.x;

    if (bid < NLSTM) {
        // ---- LSTM lane: zero private c slice, then encoder + decoder recurrence ----
        int h0 = bid * 16;
        for (int q = 0; q < 4; ++q) {
            int it = q * 256 + tid;
            c_buf[(it & 63) * 512 + h0 + (it >> 6)] = 0.f;
        }
        for (int t = 0; t < 128; ++t) {
            lstm_phase(bid, WhE, xwb + (long)t * 131072, source + t,
                       t ? enc_hs + (long)(t - 1) * 32768 : nullptr,
                       c_buf, enc_hs + (long)t * 32768, smem);
            lstm_bar(fl_enc_arr(flags), fl_enc_gen(flags), (unsigned)(t + 1));
        }
        for (int t = 0; t < 127; ++t) {
            lstm_phase(bid, WhD, xwb + (long)(128 + t) * 131072, target + t,
                       t ? dec_h + (long)(t - 1) * 32768 : enc_hs + (long)127 * 32768,
                       c_buf, dec_h + (long)t * 32768, smem);
            lstm_bar(fl_dec_arr(flags), fl_dec_gen(flags), (unsigned)(t + 1));
        }
        if (bid == 0) {
            wait_flag_bo(fl_log_done(flags), (unsigned)NLOG);
            loss_phase(sumexp, logit_t, target, out, smem);
        }
    } else if (bid < ATTN0 + NATTN) {
        // ---- attention worker: one batch column, consumes dec_h[t] as it appears ----
        const int col = bid - ATTN0;
        for (int t = 0; t < 127; ++t) {
            wait_flag_bo(fl_dec_gen(flags), (unsigned)(t + 1));
            attn_phase(col, dec_h + (long)t * 32768, enc_hs, source,
                       ctx + (long)t * 32768, smem);
            signal_done(fl_ctx_ready(flags, t));
        }
    } else if (bid < HA0 + NHA) {
        // ---- ha worker ----
        const int sub = bid - HA0;
        for (int t = 0; t < 127; ++t) {
            wait_flag_bo(fl_ctx_ready(flags, t), (unsigned)NATTN);
            ha_phase(sub, ctx + (long)t * 32768, dec_h + (long)t * 32768,
                     Wattn, attnb, ha_t + (long)t * 32768, smem);
            signal_done(fl_ha_ready(flags, t));
        }
    } else {
        // ---- logits worker: fixed vocab slice, streams all t ----
        const int sub = bid - LOG0;
        for (int t = 0; t < 127; ++t) {
            wait_flag_bo(fl_ha_ready(flags, t), (unsigned)NHA);
            logits_phase(sub, t, ha_t + (long)t * 32768, Wout, outb,
                         target, sumexp, logit_t, smem);
        }
        signal_done(fl_log_done(flags));
    }
}

// ---------------- host launcher ----------------
extern "C" void kernel_launch(void* const* d_in, const int* in_sizes, int n_in,
                              void* d_out, int out_size, void* d_ws, size_t ws_size,
                              hipStream_t stream)
{
    (void)in_sizes; (void)n_in; (void)out_size; (void)ws_size;
    const int*   source = (const int*)  d_in[0];
    const int*   target = (const int*)  d_in[1];
    const float* embS   = (const float*)d_in[2];
    const float* embT   = (const float*)d_in[3];
    const float* eWih   = (const float*)d_in[4];
    const float* eWhh   = (const float*)d_in[5];
    const float* ebih   = (const float*)d_in[6];
    const float* ebhh   = (const float*)d_in[7];
    const float* dWih   = (const float*)d_in[8];
    const float* dWhh   = (const float*)d_in[9];
    const float* dbih   = (const float*)d_in[10];
    const float* dbhh   = (const float*)d_in[11];
    const float* attnW  = (const float*)d_in[12];
    const float* attnb  = (const float*)d_in[13];
    const float* outW   = (const float*)d_in[14];
    const float* outb   = (const float*)d_in[15];
    float* out = (float*)d_out;
    char* ws = (char*)d_ws;

    // layout (dec_h/ctx overlap the encoder half of xwb: encoder xwb is consumed
    // strictly before decoder writes, and ALL accesses on both sides are sc1)
    unsigned short* enc_hs = (unsigned short*)(ws);               //  8,388,608
    unsigned short* ha_t   = (unsigned short*)(ws + 8388608);     //  8,388,608
    unsigned short* xwb    = (unsigned short*)(ws + 16777216);    // 66,846,720
    unsigned short* dec_h  = (unsigned short*)(ws + 16777216);    //  8,323,072 (overlap)
    unsigned short* ctx    = (unsigned short*)(ws + 25100288);    //  8,323,072 (overlap)
    float* c_buf           = (float*)(ws + 83623936);             //    131,072
    float* sumexp          = (float*)(ws + 83755008);             //     32,768
    float* logitt          = (float*)(ws + 83787776);             //     32,768
    unsigned short* WxE    = (unsigned short*)(ws + 83820544);    //  2,097,152
    unsigned short* WhE    = (unsigned short*)(ws + 85917696);    //  2,097,152
    unsigned short* WxD    = (unsigned short*)(ws + 88014848);    //  2,097,152
    unsigned short* WhD    = (unsigned short*)(ws + 90112000);    //  2,097,152
    unsigned short* Wattn  = (unsigned short*)(ws + 92209152);    //  1,048,576
    unsigned short* Wout   = (unsigned short*)(ws + 93257728);    // 32,768,000
    unsigned* flags        = (unsigned*)(ws + 126025728);         //   163,840 (40 pages)

    hipMemsetAsync(flags, 0, FLAGS_ARENA_BYTES, stream);
    hipMemsetAsync(sumexp, 0, 32768, stream);
    conv_lstm_w2<<<4096, 256, 0, stream>>>(WxE, WhE, eWih, eWhh);
    conv_lstm_w2<<<4096, 256, 0, stream>>>(WxD, WhD, dWih, dWhh);
    conv_plain<<<2048, 256, 0, stream>>>(Wattn, attnW, 512 * 1024);
    conv_plain<<<64000, 256, 0, stream>>>(Wout, outW, 32000 * 512);
    xw_kernel<<<255 * 32, 256, 0, stream>>>(source, target, embS, embT,
                                            ebih, ebhh, dbih, dbhh, WxE, WxD, xwb);

    seq_kernel<<<NBLK, 256, 0, stream>>>(
        source, target, attnb, outb,
        WhE, WhD, Wattn, Wout, xwb,
        enc_hs, dec_h, ctx, ha_t, c_buf, sumexp, logitt,
        out, flags);
}